// Round 12
// baseline (404.427 us; speedup 1.0000x reference)
//
#include <hip/hip_runtime.h>
#include <hip/hip_bf16.h>
#include <stdint.h>

#define NTOK 32768
#define DIM  768
#define HID  256
#define NEXP 8
#define PADC 144   // repack-tile column pad: conflict-reduced epilogue writes

typedef float f32x4 __attribute__((ext_vector_type(4)));
typedef short s16x8 __attribute__((ext_vector_type(8)));

__device__ __forceinline__ unsigned short f2bf(float f) {
  union { float f; unsigned int u; } c; c.f = f;
  unsigned int r = c.u + 0x7fffu + ((c.u >> 16) & 1u);
  return (unsigned short)(r >> 16);
}

__device__ __forceinline__ float bf2f(unsigned int u) {
  union { unsigned int x; float f; } c; c.x = u << 16; return c.f;
}

// async global -> LDS, 16B per lane. LDS dest is wave-uniform base + lane*16.
__device__ __forceinline__ void gload_lds16(const unsigned short* g, unsigned short* l) {
  __builtin_amdgcn_global_load_lds((const __attribute__((address_space(1))) void*)g,
                                   (__attribute__((address_space(3))) void*)l, 16, 0, 0);
}

// ---------------- x fp32 -> bf16 ----------------
__global__ __launch_bounds__(256) void k_cvt_x(const float* __restrict__ x,
                                               unsigned short* __restrict__ xbf) {
  int i = (blockIdx.x * 256 + threadIdx.x) * 8;
  float4 a = *(const float4*)(x + i);
  float4 b = *(const float4*)(x + i + 4);
  float f[8] = {a.x, a.y, a.z, a.w, b.x, b.y, b.z, b.w};
  unsigned short h[8];
#pragma unroll
  for (int q = 0; q < 8; ++q) h[q] = f2bf(f[q]);
  int4 vh;
  vh.x = (int)((unsigned)h[0] | ((unsigned)h[1] << 16));
  vh.y = (int)((unsigned)h[2] | ((unsigned)h[3] << 16));
  vh.z = (int)((unsigned)h[4] | ((unsigned)h[5] << 16));
  vh.w = (int)((unsigned)h[6] | ((unsigned)h[7] << 16));
  *(int4*)(xbf + i) = vh;
}

// ---------------- fp32 [R][C] -> bf16 [C][R] transpose via LDS tile ----------------
__global__ __launch_bounds__(256) void k_tr(const float* __restrict__ in,
                                            unsigned short* __restrict__ outp,
                                            int R, int C) {
  __shared__ float tile[32][33];
  int e = blockIdx.z;
  const float* ip = in + (size_t)e * R * C;
  unsigned short* op = outp + (size_t)e * R * C;
  int tx = threadIdx.x & 31, ty = threadIdx.x >> 5;  // 32x8
  int r0 = blockIdx.y * 32, c0 = blockIdx.x * 32;
#pragma unroll
  for (int i = 0; i < 4; ++i)
    tile[ty + i * 8][tx] = ip[(size_t)(r0 + ty + i * 8) * C + c0 + tx];
  __syncthreads();
#pragma unroll
  for (int i = 0; i < 4; ++i)
    op[(size_t)(c0 + ty + i * 8) * R + r0 + tx] = f2bf(tile[tx][ty + i * 8]);
}

// ---------------- gate layer 1, bf16 MFMA: hg = relu(x @ Wg1 + bg1) ----------------
// Plain bf16 (score error sigma ~3e-4); near-tie tokens get exact fp32 rescue later.
__global__ __launch_bounds__(256) void k_gmfma(const unsigned short* __restrict__ xhi,
                                               const unsigned short* __restrict__ whi,
                                               const float* __restrict__ bg1,
                                               float* __restrict__ hg) {
  int bm = blockIdx.x * 128;
  int bn = blockIdx.y * 128;

  __shared__ __align__(16) unsigned short Ah[128 * 64];
  __shared__ __align__(16) unsigned short Bh[128 * 64];

  int tid = threadIdx.x;
  int lane = tid & 63;
  int wid = tid >> 6;
  int wm = wid >> 1, wn = wid & 1;
  int ar = lane & 15, kg = lane >> 4;

  const unsigned short *sah[4], *sbh[4];
  unsigned short *dA[4], *dB[4];
#pragma unroll
  for (int i = 0; i < 4; ++i) {
    int cb0 = i * 256 + wid * 64;        // wave-uniform chunk base
    int ci = cb0 + lane;
    int row = ci >> 3;
    int cb = (ci & 7) ^ (row & 7);       // inverse-swizzled source chunk
    sah[i] = xhi + (size_t)(bm + row) * DIM + cb * 8;
    sbh[i] = whi + (size_t)(bn + row) * DIM + cb * 8;
    dA[i] = &Ah[cb0 * 8];
    dB[i] = &Bh[cb0 * 8];
  }

  f32x4 acc[4][4] = {};

  for (int kt = 0; kt < DIM / 64; ++kt) {
#pragma unroll
    for (int i = 0; i < 4; ++i) {
      gload_lds16(sah[i] + kt * 64, dA[i]);
      gload_lds16(sbh[i] + kt * 64, dB[i]);
    }
    __syncthreads();
#pragma unroll
    for (int ks = 0; ks < 2; ++ks) {
      int kc = ks * 4 + kg;
      s16x8 a[4], b[4];
#pragma unroll
      for (int m = 0; m < 4; ++m) {
        int row = wm * 64 + m * 16 + ar;
        a[m] = *(const s16x8*)&Ah[row * 64 + ((kc ^ (row & 7)) * 8)];
      }
#pragma unroll
      for (int n = 0; n < 4; ++n) {
        int row = wn * 64 + n * 16 + ar;
        b[n] = *(const s16x8*)&Bh[row * 64 + ((kc ^ (row & 7)) * 8)];
      }
#pragma unroll
      for (int m = 0; m < 4; ++m)
#pragma unroll
        for (int n = 0; n < 4; ++n)
          acc[m][n] = __builtin_amdgcn_mfma_f32_16x16x32_bf16(a[m], b[n], acc[m][n], 0, 0, 0);
    }
    __syncthreads();
  }

  // bias + relu -> hg fp32
#pragma unroll
  for (int n = 0; n < 4; ++n) {
    int col = bn + wn * 64 + n * 16 + ar;
    float bb = bg1[col];
#pragma unroll
    for (int m = 0; m < 4; ++m) {
      int rbase = bm + wm * 64 + m * 16 + kg * 4;
#pragma unroll
      for (int r = 0; r < 4; ++r)
        hg[(size_t)(rbase + r) * HID + col] = fmaxf(acc[m][n][r] + bb, 0.f);
    }
  }
}

// ---------------- gate 2a: scores from hg -> gs; flag near-ties for fp32 rescue ----------------
__global__ __launch_bounds__(256) void k_gate2a(const float* __restrict__ hg,
                                                const float* __restrict__ wg2,
                                                const float* __restrict__ bg2,
                                                float* __restrict__ gs,
                                                int* __restrict__ rcnt,
                                                int* __restrict__ rlist) {
  int tok = blockIdx.x * 256 + threadIdx.x;
  const float* hrow = hg + (size_t)tok * HID;

  float s[8];
#pragma unroll
  for (int e = 0; e < 8; ++e) s[e] = bg2[e];
#pragma unroll 8
  for (int j = 0; j < 64; ++j) {
    f32x4 hv = *(const f32x4*)(hrow + j * 4);
#pragma unroll
    for (int i = 0; i < 4; ++i) {
      const float* wr = wg2 + (j * 4 + i) * 8;
#pragma unroll
      for (int e = 0; e < 8; ++e) s[e] += hv[i] * wr[e];
    }
  }

  f32x4 o0 = {s[0], s[1], s[2], s[3]};
  f32x4 o1 = {s[4], s[5], s[6], s[7]};
  *(f32x4*)&gs[(size_t)tok * 8] = o0;
  *(f32x4*)&gs[(size_t)tok * 8 + 4] = o1;

  // top-3 scan; bf16-gate gap-error sigma ~5e-4. Threshold 0.01 = 20 sigma:
  // tokens outside the window cannot flip their top-2 set; inside -> exact fp32.
  float m1 = -3e38f, m2 = -3e38f, m3 = -3e38f;
#pragma unroll
  for (int e = 0; e < 8; ++e) {
    float v = s[e];
    if (v > m1)      { m3 = m2; m2 = m1; m1 = v; }
    else if (v > m2) { m3 = m2; m2 = v; }
    else if (v > m3) { m3 = v; }
  }
  if (m2 - m3 < 0.01f) {
    int i = atomicAdd(rcnt, 1);
    rlist[i] = tok;
  }
}

// ---------------- rescue stage 1: hr = relu(x[rlist] @ Wg1 + bg1), exact fp32 SGEMM ----------------
// Round-5-proven k_gate1 structure (128x64 tile, BK=16) + row gather + early-exit on n.
__global__ __launch_bounds__(256) void k_rsgemm(const float* __restrict__ x,
                                                const float* __restrict__ wg1,
                                                const float* __restrict__ bg1,
                                                const int* __restrict__ rcnt,
                                                const int* __restrict__ rlist,
                                                float* __restrict__ hr) {
  int n = rcnt[0];
  int row0 = blockIdx.x * 128;
  if (row0 >= n) return;
  int bn = blockIdx.y * 64;
  __shared__ __align__(16) float As[16][132];
  __shared__ __align__(16) float Bs[16][64];
  __shared__ int stok[128];
  int tid = threadIdx.x;
  if (tid < 128) stok[tid] = rlist[min(row0 + tid, n - 1)];
  __syncthreads();
  int tx = tid & 15, ty = tid >> 4;
  f32x4 acc[8] = {};
  for (int k0 = 0; k0 < DIM; k0 += 16) {
#pragma unroll
    for (int l = 0; l < 2; ++l) {
      int i4 = tid + l * 256;
      int row = i4 >> 2;
      int kq = (i4 & 3) * 4;
      float4 v = *(const float4*)&x[(size_t)stok[row] * DIM + k0 + kq];
      As[kq + 0][row] = v.x; As[kq + 1][row] = v.y;
      As[kq + 2][row] = v.z; As[kq + 3][row] = v.w;
    }
    {
      int krow = tid >> 4;
      int c4 = (tid & 15) * 4;
      *(float4*)&Bs[krow][c4] = *(const float4*)&wg1[(size_t)(k0 + krow) * HID + bn + c4];
    }
    __syncthreads();
#pragma unroll
    for (int kk = 0; kk < 16; ++kk) {
      f32x4 a0 = *(const f32x4*)&As[kk][ty * 8];
      f32x4 a1 = *(const f32x4*)&As[kk][ty * 8 + 4];
      f32x4 bv = *(const f32x4*)&Bs[kk][tx * 4];
#pragma unroll
      for (int i = 0; i < 4; ++i) acc[i]     += bv * a0[i];
#pragma unroll
      for (int i = 0; i < 4; ++i) acc[i + 4] += bv * a1[i];
    }
    __syncthreads();
  }
  f32x4 bias = *(const f32x4*)&bg1[bn + tx * 4];
#pragma unroll
  for (int i = 0; i < 8; ++i) {
    int row = ty * 8 + i;
    if (row0 + row < n) {
      f32x4 v = acc[i] + bias;
#pragma unroll
      for (int j = 0; j < 4; ++j) v[j] = fmaxf(v[j], 0.f);
      *(f32x4*)&hr[(size_t)(row0 + row) * HID + bn + tx * 4] = v;
    }
  }
}

// ---------------- rescue stage 2: exact scores from hr -> gs overwrite ----------------
__global__ __launch_bounds__(256) void k_rscore(const float* __restrict__ hr,
                                                const float* __restrict__ wg2,
                                                const float* __restrict__ bg2,
                                                const int* __restrict__ rcnt,
                                                const int* __restrict__ rlist,
                                                float* __restrict__ gs) {
  int n = rcnt[0];
  int idx = blockIdx.x * 256 + threadIdx.x;
  if (idx >= n) return;
  const float* hrow = hr + (size_t)idx * HID;
  float s[8];
#pragma unroll
  for (int e = 0; e < 8; ++e) s[e] = bg2[e];
#pragma unroll 8
  for (int j = 0; j < 64; ++j) {
    f32x4 hv = *(const f32x4*)(hrow + j * 4);
#pragma unroll
    for (int i = 0; i < 4; ++i) {
      const float* wr = wg2 + (j * 4 + i) * 8;
#pragma unroll
      for (int e = 0; e < 8; ++e) s[e] += hv[i] * wr[e];
    }
  }
  int tok = rlist[idx];
  f32x4 o0 = {s[0], s[1], s[2], s[3]};
  f32x4 o1 = {s[4], s[5], s[6], s[7]};
  *(f32x4*)&gs[(size_t)tok * 8] = o0;
  *(f32x4*)&gs[(size_t)tok * 8 + 4] = o1;
}

// ---------------- gate 2b: softmax + top2 + routing lists from gs ----------------
// wts sign-encodes rank: +w for top-1 expert entry, -w for top-2 entry.
__global__ __launch_bounds__(256) void k_gate2b(const float* __restrict__ gs,
                                                float* __restrict__ gprob,
                                                int* __restrict__ cnt,     // stride 32
                                                int* __restrict__ lists,
                                                float* __restrict__ wts) {
  __shared__ int lcnt[8];
  __shared__ int sbase[8];
  __shared__ int se1[256], se2[256], sp1[256], sp2[256];
  __shared__ float sw1[256], sw2[256];
  int tid = threadIdx.x;
  if (tid < 8) lcnt[tid] = 0;
  __syncthreads();

  int tok = blockIdx.x * 256 + tid;
  f32x4 s0v = *(const f32x4*)&gs[(size_t)tok * 8];
  f32x4 s1v = *(const f32x4*)&gs[(size_t)tok * 8 + 4];
  float s[8] = {s0v[0], s0v[1], s0v[2], s0v[3], s1v[0], s1v[1], s1v[2], s1v[3]};

  float m = s[0];
#pragma unroll
  for (int e = 1; e < 8; ++e) m = fmaxf(m, s[e]);
  float p[8]; float sum = 0.f;
#pragma unroll
  for (int e = 0; e < 8; ++e) { p[e] = expf(s[e] - m); sum += p[e]; }
  float inv = 1.f / sum;
#pragma unroll
  for (int e = 0; e < 8; ++e) p[e] *= inv;

  f32x4 o0 = {p[0], p[1], p[2], p[3]};
  f32x4 o1 = {p[4], p[5], p[6], p[7]};
  *(f32x4*)&gprob[(size_t)tok * 8] = o0;
  *(f32x4*)&gprob[(size_t)tok * 8 + 4] = o1;

  int e1 = 0; float p1 = p[0];
#pragma unroll
  for (int e = 1; e < 8; ++e) if (p[e] > p1) { p1 = p[e]; e1 = e; }
  int e2 = -1; float p2 = -1.f;
#pragma unroll
  for (int e = 0; e < 8; ++e) if (e != e1 && p[e] > p2) { p2 = p[e]; e2 = e; }
  float rinv = 1.f / (p1 + p2);

  int pos1 = atomicAdd(&lcnt[e1], 1);
  int pos2 = atomicAdd(&lcnt[e2], 1);
  se1[tid] = e1; sp1[tid] = pos1; sw1[tid] = p1 * rinv;
  se2[tid] = e2; sp2[tid] = pos2; sw2[tid] = p2 * rinv;
  __syncthreads();

  if (tid < 8) sbase[tid] = atomicAdd(&cnt[tid * 32], lcnt[tid]);
  __syncthreads();

  int a1i = sbase[se1[tid]] + sp1[tid];
  lists[se1[tid] * NTOK + a1i] = tok; wts[se1[tid] * NTOK + a1i] = sw1[tid];   // rank0: +w
  int a2i = sbase[se2[tid]] + sp2[tid];
  lists[se2[tid] * NTOK + a2i] = tok; wts[se2[tid] * NTOK + a2i] = -sw2[tid];  // rank1: -w
}

// ---------------- expert layer 1 GEMM: h = relu(x_gathered @ W1^T + b1) ----------------
// Epilogue: acc -> LDS bf16 tile (pad 144) -> 16B coalesced stores to compact h.
__global__ __launch_bounds__(256) void k_ffn1(const unsigned short* __restrict__ xbf,
                                              const unsigned short* __restrict__ w1t,
                                              const float* __restrict__ b1,
                                              const int* __restrict__ cnt,
                                              const int* __restrict__ lists,
                                              unsigned short* __restrict__ h) {
  int e = blockIdx.z;
  int c = cnt[e * 32];
  int row0 = blockIdx.x * 128;
  if (row0 >= c) return;
  int bn = blockIdx.y * 128;
  int pfx = 0;
#pragma unroll
  for (int j = 0; j < 8; ++j) if (j < e) pfx += cnt[j * 32];

  __shared__ __align__(16) unsigned short smem[128 * PADC];  // staging (32KB) U repack tile (36KB)
  __shared__ int stok[128];
  unsigned short* As = smem;
  unsigned short* Bs = smem + 128 * 64;

  int tid = threadIdx.x;
  int lane = tid & 63;
  int wid = tid >> 6;
  int wm = wid >> 1, wn = wid & 1;
  int ar = lane & 15, kg = lane >> 4;

  if (tid < 128) stok[tid] = lists[e * NTOK + min(row0 + tid, c - 1)];
  __syncthreads();

  const unsigned short* asrc[4];
  const unsigned short* bsrc[4];
  unsigned short* ldsA[4];
  unsigned short* ldsB[4];
#pragma unroll
  for (int i = 0; i < 4; ++i) {
    int cb0 = i * 256 + wid * 64;        // wave-uniform chunk base
    int ci = cb0 + lane;
    int row = ci >> 3;
    int cb = (ci & 7) ^ (row & 7);       // inverse-swizzled source chunk
    asrc[i] = xbf + (size_t)stok[row] * DIM + cb * 8;
    bsrc[i] = w1t + ((size_t)e * HID + bn + row) * DIM + cb * 8;
    ldsA[i] = &As[cb0 * 8];
    ldsB[i] = &Bs[cb0 * 8];
  }

  f32x4 acc[4][4] = {};

  for (int kt = 0; kt < DIM / 64; ++kt) {
#pragma unroll
    for (int i = 0; i < 4; ++i) {
      gload_lds16(asrc[i] + kt * 64, ldsA[i]);
      gload_lds16(bsrc[i] + kt * 64, ldsB[i]);
    }
    __syncthreads();
#pragma unroll
    for (int ks = 0; ks < 2; ++ks) {
      int kc = ks * 4 + kg;
      s16x8 a[4], b[4];
#pragma unroll
      for (int m = 0; m < 4; ++m) {
        int row = wm * 64 + m * 16 + ar;
        a[m] = *(const s16x8*)&As[row * 64 + ((kc ^ (row & 7)) * 8)];
      }
#pragma unroll
      for (int n = 0; n < 4; ++n) {
        int row = wn * 64 + n * 16 + ar;
        b[n] = *(const s16x8*)&Bs[row * 64 + ((kc ^ (row & 7)) * 8)];
      }
#pragma unroll
      for (int m = 0; m < 4; ++m)
#pragma unroll
        for (int n = 0; n < 4; ++n)
          acc[m][n] = __builtin_amdgcn_mfma_f32_16x16x32_bf16(a[m], b[n], acc[m][n], 0, 0, 0);
    }
    __syncthreads();
  }

  // bias + relu -> LDS repack tile -> coalesced 16B stores (compact rows)
#pragma unroll
  for (int n = 0; n < 4; ++n) {
    int col = wn * 64 + n * 16 + ar;             // within-tile col
    float bb = b1[e * HID + bn + col];
#pragma unroll
    for (int m = 0; m < 4; ++m) {
      int rloc = wm * 64 + m * 16 + kg * 4;
#pragma unroll
      for (int r = 0; r < 4; ++r)
        smem[(rloc + r) * PADC + col] = f2bf(fmaxf(acc[m][n][r] + bb, 0.f));
    }
  }
  __syncthreads();
  int hbase = pfx + row0;
#pragma unroll
  for (int q = 0; q < 8; ++q) {
    int ci = tid + q * 256;
    int row = ci >> 4, ch = ci & 15;
    if (row0 + row < c) {
      int4 v = *(const int4*)&smem[row * PADC + ch * 8];
      *(int4*)&h[(size_t)(hbase + row) * HID + bn + ch * 8] = v;
    }
  }
}

// ---------------- expert layer 2 GEMM + rank-split partial store (or atomic fallback) ----------------
template <bool STORE_PART>
__global__ __launch_bounds__(256) void k_ffn2(const unsigned short* __restrict__ h,
                                              const unsigned short* __restrict__ w2t,
                                              const float* __restrict__ b2,
                                              const int* __restrict__ cnt,
                                              const int* __restrict__ lists,
                                              const float* __restrict__ wts,
                                              unsigned short* __restrict__ part0,
                                              unsigned short* __restrict__ part1,
                                              float* __restrict__ out) {
  int e = blockIdx.z;
  int c = cnt[e * 32];
  int row0 = blockIdx.x * 128;
  if (row0 >= c) return;
  int bn = blockIdx.y * 128;
  int pfx = 0;
#pragma unroll
  for (int j = 0; j < 8; ++j) if (j < e) pfx += cnt[j * 32];

  __shared__ __align__(16) unsigned short smem[128 * PADC];  // staging (32KB) U repack tile (36KB)
  __shared__ int stok[128];
  __shared__ float swt[128];
  unsigned short* As = smem;
  unsigned short* Bs = smem + 128 * 64;

  int tid = threadIdx.x;
  int lane = tid & 63;
  int wid = tid >> 6;
  int wm = wid >> 1, wn = wid & 1;
  int ar = lane & 15, kg = lane >> 4;

  if (tid < 128) {
    int r = row0 + tid;
    stok[tid] = (r < c) ? lists[e * NTOK + r] : 0;
    swt[tid]  = (r < c) ? wts[e * NTOK + r] : 0.f;
  }
  __syncthreads();

  const unsigned short* asrc[4];
  const unsigned short* bsrc[4];
  unsigned short* ldsA[4];
  unsigned short* ldsB[4];
#pragma unroll
  for (int i = 0; i < 4; ++i) {
    int cb0 = i * 256 + wid * 64;
    int ci = cb0 + lane;
    int row = ci >> 3;
    int cb = (ci & 7) ^ (row & 7);
    asrc[i] = h + (size_t)(pfx + row0 + row) * HID + cb * 8;
    bsrc[i] = w2t + ((size_t)e * DIM + bn + row) * HID + cb * 8;
    ldsA[i] = &As[cb0 * 8];
    ldsB[i] = &Bs[cb0 * 8];
  }

  f32x4 acc[4][4] = {};

  for (int kt = 0; kt < HID / 64; ++kt) {
#pragma unroll
    for (int i = 0; i < 4; ++i) {
      gload_lds16(asrc[i] + kt * 64, ldsA[i]);
      gload_lds16(bsrc[i] + kt * 64, ldsB[i]);
    }
    __syncthreads();
#pragma unroll
    for (int ks = 0; ks < 2; ++ks) {
      int kc = ks * 4 + kg;
      s16x8 a[4], b[4];
#pragma unroll
      for (int m = 0; m < 4; ++m) {
        int row = wm * 64 + m * 16 + ar;
        a[m] = *(const s16x8*)&As[row * 64 + ((kc ^ (row & 7)) * 8)];
      }
#pragma unroll
      for (int n = 0; n < 4; ++n) {
        int row = wn * 64 + n * 16 + ar;
        b[n] = *(const s16x8*)&Bs[row * 64 + ((kc ^ (row & 7)) * 8)];
      }
#pragma unroll
      for (int m = 0; m < 4; ++m)
#pragma unroll
        for (int n = 0; n < 4; ++n)
          acc[m][n] = __builtin_amdgcn_mfma_f32_16x16x32_bf16(a[m], b[n], acc[m][n], 0, 0, 0);
    }
    __syncthreads();
  }

  if constexpr (STORE_PART) {
    // weighted bias epilogue -> LDS repack tile -> coalesced 16B stores per token row
#pragma unroll
    for (int n = 0; n < 4; ++n) {
      int col = wn * 64 + n * 16 + ar;           // within-tile col
      float bb = b2[e * DIM + bn + col];
#pragma unroll
      for (int m = 0; m < 4; ++m) {
        int rloc = wm * 64 + m * 16 + kg * 4;
#pragma unroll
        for (int r = 0; r < 4; ++r) {
          float w = swt[rloc + r];
          smem[(rloc + r) * PADC + col] = f2bf((acc[m][n][r] + bb) * fabsf(w));
        }
      }
    }
    __syncthreads();
#pragma unroll
    for (int q = 0; q < 8; ++q) {
      int ci = tid + q * 256;
      int row = ci >> 4, ch = ci & 15;
      float w = swt[row];
      if (w != 0.f) {
        unsigned short* dst = (w > 0.f) ? part0 : part1;
        int4 v = *(const int4*)&smem[row * PADC + ch * 8];
        *(int4*)&dst[(size_t)stok[row] * DIM + bn + ch * 8] = v;
      }
    }
  } else {
    // atomic fallback
#pragma unroll
    for (int n = 0; n < 4; ++n) {
      int col = bn + wn * 64 + n * 16 + ar;
      float bb = b2[e * DIM + col];
#pragma unroll
      for (int m = 0; m < 4; ++m) {
        int rloc = wm * 64 + m * 16 + kg * 4;
#pragma unroll
        for (int r = 0; r < 4; ++r) {
          float w = swt[rloc + r];
          if (w != 0.f) {
            float v = (acc[m][n][r] + bb) * fabsf(w);
            atomicAdd(&out[(size_t)stok[rloc + r] * DIM + col], v);
          }
        }
      }
    }
  }
}

// ---------------- combine: out = part0 + part1 (streaming) ----------------
__global__ __launch_bounds__(256) void k_combine(const unsigned short* __restrict__ p0,
                                                 const unsigned short* __restrict__ p1,
                                                 float* __restrict__ out) {
  size_t i = ((size_t)blockIdx.x * 256 + threadIdx.x) * 8;
  int4 a = *(const int4*)(p0 + i);
  int4 b = *(const int4*)(p1 + i);
  unsigned int ua[4] = {(unsigned)a.x, (unsigned)a.y, (unsigned)a.z, (unsigned)a.w};
  unsigned int ub[4] = {(unsigned)b.x, (unsigned)b.y, (unsigned)b.z, (unsigned)b.w};
  float o[8];
#pragma unroll
  for (int q = 0; q < 4; ++q) {
    o[q * 2 + 0] = bf2f(ua[q] & 0xffffu) + bf2f(ub[q] & 0xffffu);
    o[q * 2 + 1] = bf2f(ua[q] >> 16)     + bf2f(ub[q] >> 16);
  }
  *(float4*)(out + i)     = *(float4*)&o[0];
  *(float4*)(out + i + 4) = *(float4*)&o[4];
}

extern "C" void kernel_launch(void* const* d_in, const int* in_sizes, int n_in,
                              void* d_out, int out_size, void* d_ws, size_t ws_size,
                              hipStream_t stream) {
  const float* x   = (const float*)d_in[0];
  const float* W1  = (const float*)d_in[1];
  const float* b1  = (const float*)d_in[2];
  const float* W2  = (const float*)d_in[3];
  const float* b2  = (const float*)d_in[4];
  const float* Wg1 = (const float*)d_in[5];
  const float* bg1 = (const float*)d_in[6];
  const float* Wg2 = (const float*)d_in[7];
  const float* bg2 = (const float*)d_in[8];
  float* out = (float*)d_out;                       // [N][768] then [N][8]
  float* gprob = out + (size_t)NTOK * DIM;

  char* ws = (char*)d_ws;
  size_t off = 0;
  auto alloc = [&](size_t bytes) { void* pp = ws + off; off += (bytes + 255) & ~(size_t)255; return pp; };
  unsigned short* xbf = (unsigned short*)alloc((size_t)NTOK * DIM * 2);
  unsigned short* w1t = (unsigned short*)alloc((size_t)NEXP * HID * DIM * 2);
  unsigned short* w2t = (unsigned short*)alloc((size_t)NEXP * DIM * HID * 2);
  float* hg = (float*)alloc((size_t)NTOK * HID * 4);
  int* cnt = (int*)alloc(NEXP * 32 * 4);            // 128B-padded counters
  int* lists = (int*)alloc((size_t)NEXP * NTOK * 4);
  float* wts = (float*)alloc((size_t)NEXP * NTOK * 4);
  unsigned short* part0 = (unsigned short*)alloc((size_t)NTOK * DIM * 2);
  unsigned short* part1 = (unsigned short*)alloc((size_t)NTOK * DIM * 2);
  bool store_mode = (off <= ws_size);

  // Gate scratch overlays part0 (written only by k_ffn2/k_combine, strictly after
  // every reader of these aliases in stream order). Fallback: dedicated allocs.
  unsigned short* wg1t;
  float* gs; int* rcnt; int* rlist; float* hr;
  if (store_mode) {
    wg1t = part0;                                    // [0, 384KB)
    char* p0b = (char*)part0;
    gs    = (float*)(p0b + (1u << 20));              // [1MB, 2MB)
    rcnt  = (int*)(p0b + 9 * (1u << 18));            // 2.25MB
    rlist = (int*)(p0b + 10 * (1u << 18));           // [2.5MB, +128KB)
    hr    = (float*)(p0b + (4u << 20));              // [4MB, 36MB) worst case
  } else {
    wg1t  = (unsigned short*)alloc((size_t)DIM * HID * 2);
    gs    = (float*)alloc((size_t)NTOK * 8 * 4);
    rcnt  = (int*)alloc(256);
    rlist = (int*)alloc((size_t)NTOK * 4);
    hr    = (float*)alloc((size_t)NTOK * HID * 4);
  }

  // h (65536 compact rows x 256 bf16 = 32MB) reuses hg's 32MB (gate2a finishes first).
  unsigned short* h = (unsigned short*)hg;

  hipMemsetAsync(cnt, 0, NEXP * 32 * sizeof(int), stream);
  hipMemsetAsync(rcnt, 0, sizeof(int), stream);
  if (!store_mode)
    hipMemsetAsync(d_out, 0, (size_t)NTOK * DIM * sizeof(float), stream);

  k_cvt_x<<<(NTOK * DIM) / (256 * 8), 256, 0, stream>>>(x, xbf);
  k_tr<<<dim3(HID / 32, DIM / 32, 1), 256, 0, stream>>>(Wg1, wg1t, DIM, HID);   // -> wg1t[h][d]
  k_tr<<<dim3(HID / 32, DIM / 32, NEXP), 256, 0, stream>>>(W1, w1t, DIM, HID);  // -> w1t[e][h][d]
  k_tr<<<dim3(DIM / 32, HID / 32, NEXP), 256, 0, stream>>>(W2, w2t, HID, DIM);  // -> w2t[e][d][h]
  k_gmfma<<<dim3(NTOK / 128, HID / 128), 256, 0, stream>>>(xbf, wg1t, bg1, hg);
  k_gate2a<<<NTOK / 256, 256, 0, stream>>>(hg, Wg2, bg2, gs, rcnt, rlist);
  k_rsgemm<<<dim3(NTOK / 128, HID / 64), 256, 0, stream>>>(x, Wg1, bg1, rcnt, rlist, hr);
  k_rscore<<<NTOK / 256, 256, 0, stream>>>(hr, Wg2, bg2, rcnt, rlist, gs);
  k_gate2b<<<NTOK / 256, 256, 0, stream>>>(gs, gprob, cnt, lists, wts);
  k_ffn1<<<dim3(NTOK / 128, 2, NEXP), 256, 0, stream>>>(xbf, w1t, b1, cnt, lists, h);
  if (store_mode) {
    k_ffn2<true><<<dim3(NTOK / 128, 6, NEXP), 256, 0, stream>>>(h, w2t, b2, cnt, lists, wts, part0, part1, out);
    k_combine<<<(NTOK * DIM) / (256 * 8), 256, 0, stream>>>(part0, part1, out);
  } else {
    k_ffn2<false><<<dim3(NTOK / 128, 6, NEXP), 256, 0, stream>>>(h, w2t, b2, cnt, lists, wts, part0, part1, out);
  }
}

// Round 13
// 385.995 us; speedup vs baseline: 1.0478x; 1.0478x over previous
//
#include <hip/hip_runtime.h>
#include <hip/hip_bf16.h>
#include <stdint.h>

#define NTOK 32768
#define DIM  768
#define HID  256
#define NEXP 8
#define PADC 144   // repack-tile column pad: conflict-reduced epilogue writes

typedef float f32x4 __attribute__((ext_vector_type(4)));
typedef short s16x8 __attribute__((ext_vector_type(8)));

__device__ __forceinline__ unsigned short f2bf(float f) {
  union { float f; unsigned int u; } c; c.f = f;
  unsigned int r = c.u + 0x7fffu + ((c.u >> 16) & 1u);
  return (unsigned short)(r >> 16);
}

__device__ __forceinline__ float bf2f(unsigned int u) {
  union { unsigned int x; float f; } c; c.x = u << 16; return c.f;
}

// async global -> LDS, 16B per lane. LDS dest is wave-uniform base + lane*16.
__device__ __forceinline__ void gload_lds16(const unsigned short* g, unsigned short* l) {
  __builtin_amdgcn_global_load_lds((const __attribute__((address_space(1))) void*)g,
                                   (__attribute__((address_space(3))) void*)l, 16, 0, 0);
}

// ---------------- x fp32 -> bf16 ----------------
__global__ __launch_bounds__(256) void k_cvt_x(const float* __restrict__ x,
                                               unsigned short* __restrict__ xbf) {
  int i = (blockIdx.x * 256 + threadIdx.x) * 8;
  float4 a = *(const float4*)(x + i);
  float4 b = *(const float4*)(x + i + 4);
  float f[8] = {a.x, a.y, a.z, a.w, b.x, b.y, b.z, b.w};
  unsigned short h[8];
#pragma unroll
  for (int q = 0; q < 8; ++q) h[q] = f2bf(f[q]);
  int4 vh;
  vh.x = (int)((unsigned)h[0] | ((unsigned)h[1] << 16));
  vh.y = (int)((unsigned)h[2] | ((unsigned)h[3] << 16));
  vh.z = (int)((unsigned)h[4] | ((unsigned)h[5] << 16));
  vh.w = (int)((unsigned)h[6] | ((unsigned)h[7] << 16));
  *(int4*)(xbf + i) = vh;
}

// ---------------- fp32 [R][C] -> bf16 [C][R] transpose via LDS tile ----------------
__global__ __launch_bounds__(256) void k_tr(const float* __restrict__ in,
                                            unsigned short* __restrict__ outp,
                                            int R, int C) {
  __shared__ float tile[32][33];
  int e = blockIdx.z;
  const float* ip = in + (size_t)e * R * C;
  unsigned short* op = outp + (size_t)e * R * C;
  int tx = threadIdx.x & 31, ty = threadIdx.x >> 5;  // 32x8
  int r0 = blockIdx.y * 32, c0 = blockIdx.x * 32;
#pragma unroll
  for (int i = 0; i < 4; ++i)
    tile[ty + i * 8][tx] = ip[(size_t)(r0 + ty + i * 8) * C + c0 + tx];
  __syncthreads();
#pragma unroll
  for (int i = 0; i < 4; ++i)
    op[(size_t)(c0 + ty + i * 8) * R + r0 + tx] = f2bf(tile[tx][ty + i * 8]);
}

// ---------------- gate layer 1, bf16 MFMA: hg = relu(x @ Wg1 + bg1) ----------------
// Plain bf16 (gap-error sigma ~1.7e-3); near-tie tokens get exact fp32 rescue later.
__global__ __launch_bounds__(256) void k_gmfma(const unsigned short* __restrict__ xhi,
                                               const unsigned short* __restrict__ whi,
                                               const float* __restrict__ bg1,
                                               float* __restrict__ hg) {
  int bm = blockIdx.x * 128;
  int bn = blockIdx.y * 128;

  __shared__ __align__(16) unsigned short Ah[128 * 64];
  __shared__ __align__(16) unsigned short Bh[128 * 64];

  int tid = threadIdx.x;
  int lane = tid & 63;
  int wid = tid >> 6;
  int wm = wid >> 1, wn = wid & 1;
  int ar = lane & 15, kg = lane >> 4;

  const unsigned short *sah[4], *sbh[4];
  unsigned short *dA[4], *dB[4];
#pragma unroll
  for (int i = 0; i < 4; ++i) {
    int cb0 = i * 256 + wid * 64;        // wave-uniform chunk base
    int ci = cb0 + lane;
    int row = ci >> 3;
    int cb = (ci & 7) ^ (row & 7);       // inverse-swizzled source chunk
    sah[i] = xhi + (size_t)(bm + row) * DIM + cb * 8;
    sbh[i] = whi + (size_t)(bn + row) * DIM + cb * 8;
    dA[i] = &Ah[cb0 * 8];
    dB[i] = &Bh[cb0 * 8];
  }

  f32x4 acc[4][4] = {};

  for (int kt = 0; kt < DIM / 64; ++kt) {
#pragma unroll
    for (int i = 0; i < 4; ++i) {
      gload_lds16(sah[i] + kt * 64, dA[i]);
      gload_lds16(sbh[i] + kt * 64, dB[i]);
    }
    __syncthreads();
#pragma unroll
    for (int ks = 0; ks < 2; ++ks) {
      int kc = ks * 4 + kg;
      s16x8 a[4], b[4];
#pragma unroll
      for (int m = 0; m < 4; ++m) {
        int row = wm * 64 + m * 16 + ar;
        a[m] = *(const s16x8*)&Ah[row * 64 + ((kc ^ (row & 7)) * 8)];
      }
#pragma unroll
      for (int n = 0; n < 4; ++n) {
        int row = wn * 64 + n * 16 + ar;
        b[n] = *(const s16x8*)&Bh[row * 64 + ((kc ^ (row & 7)) * 8)];
      }
#pragma unroll
      for (int m = 0; m < 4; ++m)
#pragma unroll
        for (int n = 0; n < 4; ++n)
          acc[m][n] = __builtin_amdgcn_mfma_f32_16x16x32_bf16(a[m], b[n], acc[m][n], 0, 0, 0);
    }
    __syncthreads();
  }

  // bias + relu -> hg fp32
#pragma unroll
  for (int n = 0; n < 4; ++n) {
    int col = bn + wn * 64 + n * 16 + ar;
    float bb = bg1[col];
#pragma unroll
    for (int m = 0; m < 4; ++m) {
      int rbase = bm + wm * 64 + m * 16 + kg * 4;
#pragma unroll
      for (int r = 0; r < 4; ++r)
        hg[(size_t)(rbase + r) * HID + col] = fmaxf(acc[m][n][r] + bb, 0.f);
    }
  }
}

// ---------------- gate 2a: scores from hg -> gs; flag near-ties for fp32 rescue ----------------
__global__ __launch_bounds__(256) void k_gate2a(const float* __restrict__ hg,
                                                const float* __restrict__ wg2,
                                                const float* __restrict__ bg2,
                                                float* __restrict__ gs,
                                                int* __restrict__ rcnt,
                                                int* __restrict__ rlist) {
  int tok = blockIdx.x * 256 + threadIdx.x;
  const float* hrow = hg + (size_t)tok * HID;

  float s[8];
#pragma unroll
  for (int e = 0; e < 8; ++e) s[e] = bg2[e];
#pragma unroll 8
  for (int j = 0; j < 64; ++j) {
    f32x4 hv = *(const f32x4*)(hrow + j * 4);
#pragma unroll
    for (int i = 0; i < 4; ++i) {
      const float* wr = wg2 + (j * 4 + i) * 8;
#pragma unroll
      for (int e = 0; e < 8; ++e) s[e] += hv[i] * wr[e];
    }
  }

  f32x4 o0 = {s[0], s[1], s[2], s[3]};
  f32x4 o1 = {s[4], s[5], s[6], s[7]};
  *(f32x4*)&gs[(size_t)tok * 8] = o0;
  *(f32x4*)&gs[(size_t)tok * 8 + 4] = o1;

  // top-3 scan; bf16-gate gap-error sigma ~1.7e-3. Threshold 0.01 = ~6 sigma:
  // tokens outside the window cannot flip their top-2 set; inside -> exact fp32.
  float m1 = -3e38f, m2 = -3e38f, m3 = -3e38f;
#pragma unroll
  for (int e = 0; e < 8; ++e) {
    float v = s[e];
    if (v > m1)      { m3 = m2; m2 = m1; m1 = v; }
    else if (v > m2) { m3 = m2; m2 = v; }
    else if (v > m3) { m3 = v; }
  }
  if (m2 - m3 < 0.01f) {
    int i = atomicAdd(rcnt, 1);
    rlist[i] = tok;
  }
}

// ---------------- rescue: exact fp32 gate recompute for flagged tokens ----------------
// Block-per-token (grid-stride over 2048). 8 independent accumulators + unroll
// keep ~32 loads in flight; dependent-FMA chain is 96 deep, not 768. (round-8-proven)
__global__ __launch_bounds__(256) void k_rescue(const float* __restrict__ x,
                                                const float* __restrict__ wg1,
                                                const float* __restrict__ bg1,
                                                const float* __restrict__ wg2,
                                                const float* __restrict__ bg2,
                                                const int* __restrict__ rcnt,
                                                const int* __restrict__ rlist,
                                                float* __restrict__ gs) {
  __shared__ float xs[DIM];
  __shared__ float ps[4][8];
  int n = rcnt[0];
  int tid = threadIdx.x;
  int lane = tid & 63, wid = tid >> 6;
  for (int idx = blockIdx.x; idx < n; idx += 2048) {
    int tok = rlist[idx];
    __syncthreads();  // protect xs/ps reuse across iterations
#pragma unroll
    for (int q = 0; q < 3; ++q) xs[tid + q * 256] = x[(size_t)tok * DIM + tid + q * 256];
    __syncthreads();
    const float* wcol = wg1 + tid;               // tid = hidden unit (HID==256)
    float pa[8] = {};
#pragma unroll 4
    for (int k0 = 0; k0 < DIM; k0 += 8) {
#pragma unroll
      for (int q = 0; q < 8; ++q)
        pa[q] = fmaf(xs[k0 + q], wcol[(size_t)(k0 + q) * HID], pa[q]);
    }
    float acc = bg1[tid] +
                (((pa[0] + pa[1]) + (pa[2] + pa[3])) + ((pa[4] + pa[5]) + (pa[6] + pa[7])));
    float hj = fmaxf(acc, 0.f);
    float p[8];
#pragma unroll
    for (int e = 0; e < 8; ++e) p[e] = hj * wg2[tid * 8 + e];
#pragma unroll
    for (int off = 32; off >= 1; off >>= 1) {
#pragma unroll
      for (int e = 0; e < 8; ++e) p[e] += __shfl_xor(p[e], off);
    }
    if (lane == 0) {
#pragma unroll
      for (int e = 0; e < 8; ++e) ps[wid][e] = p[e];
    }
    __syncthreads();
    if (tid < 8)
      gs[(size_t)tok * 8 + tid] = bg2[tid] + ps[0][tid] + ps[1][tid] + ps[2][tid] + ps[3][tid];
  }
}

// ---------------- gate 2b: softmax + top2 + routing lists from gs ----------------
// wts sign-encodes rank: +w for top-1 expert entry, -w for top-2 entry.
__global__ __launch_bounds__(256) void k_gate2b(const float* __restrict__ gs,
                                                float* __restrict__ gprob,
                                                int* __restrict__ cnt,     // stride 32
                                                int* __restrict__ lists,
                                                float* __restrict__ wts) {
  __shared__ int lcnt[8];
  __shared__ int sbase[8];
  __shared__ int se1[256], se2[256], sp1[256], sp2[256];
  __shared__ float sw1[256], sw2[256];
  int tid = threadIdx.x;
  if (tid < 8) lcnt[tid] = 0;
  __syncthreads();

  int tok = blockIdx.x * 256 + tid;
  f32x4 s0v = *(const f32x4*)&gs[(size_t)tok * 8];
  f32x4 s1v = *(const f32x4*)&gs[(size_t)tok * 8 + 4];
  float s[8] = {s0v[0], s0v[1], s0v[2], s0v[3], s1v[0], s1v[1], s1v[2], s1v[3]};

  float m = s[0];
#pragma unroll
  for (int e = 1; e < 8; ++e) m = fmaxf(m, s[e]);
  float p[8]; float sum = 0.f;
#pragma unroll
  for (int e = 0; e < 8; ++e) { p[e] = expf(s[e] - m); sum += p[e]; }
  float inv = 1.f / sum;
#pragma unroll
  for (int e = 0; e < 8; ++e) p[e] *= inv;

  f32x4 o0 = {p[0], p[1], p[2], p[3]};
  f32x4 o1 = {p[4], p[5], p[6], p[7]};
  *(f32x4*)&gprob[(size_t)tok * 8] = o0;
  *(f32x4*)&gprob[(size_t)tok * 8 + 4] = o1;

  int e1 = 0; float p1 = p[0];
#pragma unroll
  for (int e = 1; e < 8; ++e) if (p[e] > p1) { p1 = p[e]; e1 = e; }
  int e2 = -1; float p2 = -1.f;
#pragma unroll
  for (int e = 0; e < 8; ++e) if (e != e1 && p[e] > p2) { p2 = p[e]; e2 = e; }
  float rinv = 1.f / (p1 + p2);

  int pos1 = atomicAdd(&lcnt[e1], 1);
  int pos2 = atomicAdd(&lcnt[e2], 1);
  se1[tid] = e1; sp1[tid] = pos1; sw1[tid] = p1 * rinv;
  se2[tid] = e2; sp2[tid] = pos2; sw2[tid] = p2 * rinv;
  __syncthreads();

  if (tid < 8) sbase[tid] = atomicAdd(&cnt[tid * 32], lcnt[tid]);
  __syncthreads();

  int a1i = sbase[se1[tid]] + sp1[tid];
  lists[se1[tid] * NTOK + a1i] = tok; wts[se1[tid] * NTOK + a1i] = sw1[tid];   // rank0: +w
  int a2i = sbase[se2[tid]] + sp2[tid];
  lists[se2[tid] * NTOK + a2i] = tok; wts[se2[tid] * NTOK + a2i] = -sw2[tid];  // rank1: -w
}

// ---------------- expert layer 1 GEMM: h = relu(x_gathered @ W1^T + b1) ----------------
// Epilogue: acc -> LDS bf16 tile (pad 144) -> 16B coalesced stores to compact h.
__global__ __launch_bounds__(256) void k_ffn1(const unsigned short* __restrict__ xbf,
                                              const unsigned short* __restrict__ w1t,
                                              const float* __restrict__ b1,
                                              const int* __restrict__ cnt,
                                              const int* __restrict__ lists,
                                              unsigned short* __restrict__ h) {
  int e = blockIdx.z;
  int c = cnt[e * 32];
  int row0 = blockIdx.x * 128;
  if (row0 >= c) return;
  int bn = blockIdx.y * 128;
  int pfx = 0;
#pragma unroll
  for (int j = 0; j < 8; ++j) if (j < e) pfx += cnt[j * 32];

  __shared__ __align__(16) unsigned short smem[128 * PADC];  // staging (32KB) U repack tile (36KB)
  __shared__ int stok[128];
  unsigned short* As = smem;
  unsigned short* Bs = smem + 128 * 64;

  int tid = threadIdx.x;
  int lane = tid & 63;
  int wid = tid >> 6;
  int wm = wid >> 1, wn = wid & 1;
  int ar = lane & 15, kg = lane >> 4;

  if (tid < 128) stok[tid] = lists[e * NTOK + min(row0 + tid, c - 1)];
  __syncthreads();

  const unsigned short* asrc[4];
  const unsigned short* bsrc[4];
  unsigned short* ldsA[4];
  unsigned short* ldsB[4];
#pragma unroll
  for (int i = 0; i < 4; ++i) {
    int cb0 = i * 256 + wid * 64;        // wave-uniform chunk base
    int ci = cb0 + lane;
    int row = ci >> 3;
    int cb = (ci & 7) ^ (row & 7);       // inverse-swizzled source chunk
    asrc[i] = xbf + (size_t)stok[row] * DIM + cb * 8;
    bsrc[i] = w1t + ((size_t)e * HID + bn + row) * DIM + cb * 8;
    ldsA[i] = &As[cb0 * 8];
    ldsB[i] = &Bs[cb0 * 8];
  }

  f32x4 acc[4][4] = {};

  for (int kt = 0; kt < DIM / 64; ++kt) {
#pragma unroll
    for (int i = 0; i < 4; ++i) {
      gload_lds16(asrc[i] + kt * 64, ldsA[i]);
      gload_lds16(bsrc[i] + kt * 64, ldsB[i]);
    }
    __syncthreads();
#pragma unroll
    for (int ks = 0; ks < 2; ++ks) {
      int kc = ks * 4 + kg;
      s16x8 a[4], b[4];
#pragma unroll
      for (int m = 0; m < 4; ++m) {
        int row = wm * 64 + m * 16 + ar;
        a[m] = *(const s16x8*)&As[row * 64 + ((kc ^ (row & 7)) * 8)];
      }
#pragma unroll
      for (int n = 0; n < 4; ++n) {
        int row = wn * 64 + n * 16 + ar;
        b[n] = *(const s16x8*)&Bs[row * 64 + ((kc ^ (row & 7)) * 8)];
      }
#pragma unroll
      for (int m = 0; m < 4; ++m)
#pragma unroll
        for (int n = 0; n < 4; ++n)
          acc[m][n] = __builtin_amdgcn_mfma_f32_16x16x32_bf16(a[m], b[n], acc[m][n], 0, 0, 0);
    }
    __syncthreads();
  }

  // bias + relu -> LDS repack tile -> coalesced 16B stores (compact rows)
#pragma unroll
  for (int n = 0; n < 4; ++n) {
    int col = wn * 64 + n * 16 + ar;             // within-tile col
    float bb = b1[e * HID + bn + col];
#pragma unroll
    for (int m = 0; m < 4; ++m) {
      int rloc = wm * 64 + m * 16 + kg * 4;
#pragma unroll
      for (int r = 0; r < 4; ++r)
        smem[(rloc + r) * PADC + col] = f2bf(fmaxf(acc[m][n][r] + bb, 0.f));
    }
  }
  __syncthreads();
  int hbase = pfx + row0;
#pragma unroll
  for (int q = 0; q < 8; ++q) {
    int ci = tid + q * 256;
    int row = ci >> 4, ch = ci & 15;
    if (row0 + row < c) {
      int4 v = *(const int4*)&smem[row * PADC + ch * 8];
      *(int4*)&h[(size_t)(hbase + row) * HID + bn + ch * 8] = v;
    }
  }
}

// ---------------- expert layer 2 GEMM, 128x256 tile + rank-split partial store ----------------
// A (h row-tile) read 3x instead of 6x. Two 128-col halves repack through one LDS tile.
template <bool STORE_PART>
__global__ __launch_bounds__(256) void k_ffn2(const unsigned short* __restrict__ h,
                                              const unsigned short* __restrict__ w2t,
                                              const float* __restrict__ b2,
                                              const int* __restrict__ cnt,
                                              const int* __restrict__ lists,
                                              const float* __restrict__ wts,
                                              unsigned short* __restrict__ part0,
                                              unsigned short* __restrict__ part1,
                                              float* __restrict__ out) {
  int e = blockIdx.z;
  int c = cnt[e * 32];
  int row0 = blockIdx.x * 128;
  if (row0 >= c) return;
  int bn = blockIdx.y * 256;
  int pfx = 0;
#pragma unroll
  for (int j = 0; j < 8; ++j) if (j < e) pfx += cnt[j * 32];

  __shared__ __align__(16) unsigned short smem[128 * 64 + 256 * 64];  // 48KB staging U 36KB repack
  __shared__ int stok[128];
  __shared__ float swt[128];
  unsigned short* As = smem;            // 128x64 (16KB)
  unsigned short* Bs = smem + 128 * 64; // 256x64 (32KB)

  int tid = threadIdx.x;
  int lane = tid & 63;
  int wid = tid >> 6;
  int wm = wid >> 1, wn = wid & 1;      // wave: 64 rows x 128 cols
  int ar = lane & 15, kg = lane >> 4;

  if (tid < 128) {
    int r = row0 + tid;
    stok[tid] = (r < c) ? lists[e * NTOK + r] : 0;
    swt[tid]  = (r < c) ? wts[e * NTOK + r] : 0.f;
  }
  __syncthreads();

  const unsigned short* asrc[4];
  unsigned short* ldsA[4];
#pragma unroll
  for (int i = 0; i < 4; ++i) {
    int cb0 = i * 256 + wid * 64;
    int ci = cb0 + lane;
    int row = ci >> 3;
    int cb = (ci & 7) ^ (row & 7);
    asrc[i] = h + (size_t)(pfx + row0 + row) * HID + cb * 8;
    ldsA[i] = &As[cb0 * 8];
  }
  const unsigned short* bsrc[8];
  unsigned short* ldsB[8];
#pragma unroll
  for (int i = 0; i < 8; ++i) {
    int cb0 = i * 256 + wid * 64;       // 0..2047 chunks of the 256x64 B tile
    int ci = cb0 + lane;
    int row = ci >> 3;                  // 0..255
    int cb = (ci & 7) ^ (row & 7);
    bsrc[i] = w2t + ((size_t)e * DIM + bn + row) * HID + cb * 8;
    ldsB[i] = &Bs[cb0 * 8];
  }

  f32x4 acc[4][8] = {};

  for (int kt = 0; kt < HID / 64; ++kt) {
#pragma unroll
    for (int i = 0; i < 4; ++i) gload_lds16(asrc[i] + kt * 64, ldsA[i]);
#pragma unroll
    for (int i = 0; i < 8; ++i) gload_lds16(bsrc[i] + kt * 64, ldsB[i]);
    __syncthreads();
#pragma unroll
    for (int ks = 0; ks < 2; ++ks) {
      int kc = ks * 4 + kg;
      s16x8 a[4], b[8];
#pragma unroll
      for (int m = 0; m < 4; ++m) {
        int row = wm * 64 + m * 16 + ar;
        a[m] = *(const s16x8*)&As[row * 64 + ((kc ^ (row & 7)) * 8)];
      }
#pragma unroll
      for (int n = 0; n < 8; ++n) {
        int row = wn * 128 + n * 16 + ar;
        b[n] = *(const s16x8*)&Bs[row * 64 + ((kc ^ (row & 7)) * 8)];
      }
#pragma unroll
      for (int m = 0; m < 4; ++m)
#pragma unroll
        for (int n = 0; n < 8; ++n)
          acc[m][n] = __builtin_amdgcn_mfma_f32_16x16x32_bf16(a[m], b[n], acc[m][n], 0, 0, 0);
    }
    __syncthreads();
  }

  if constexpr (STORE_PART) {
    // two 128-col halves through the same repack tile; waves with wn==half own the write
#pragma unroll 1
    for (int half = 0; half < 2; ++half) {
      if (wn == half) {
#pragma unroll
        for (int n = 0; n < 8; ++n) {
          int col = n * 16 + ar;                 // 0..127 within half
          float bb = b2[e * DIM + bn + half * 128 + col];
#pragma unroll
          for (int m = 0; m < 4; ++m) {
            int rloc = wm * 64 + m * 16 + kg * 4;
#pragma unroll
            for (int r = 0; r < 4; ++r) {
              float w = swt[rloc + r];
              smem[(rloc + r) * PADC + col] = f2bf((acc[m][n][r] + bb) * fabsf(w));
            }
          }
        }
      }
      __syncthreads();
#pragma unroll
      for (int q = 0; q < 8; ++q) {
        int ci = tid + q * 256;
        int row = ci >> 4, ch = ci & 15;
        float w = swt[row];
        if (w != 0.f) {
          unsigned short* dst = (w > 0.f) ? part0 : part1;
          int4 v = *(const int4*)&smem[row * PADC + ch * 8];
          *(int4*)&dst[(size_t)stok[row] * DIM + bn + half * 128 + ch * 8] = v;
        }
      }
      __syncthreads();
    }
  } else {
    // atomic fallback
#pragma unroll
    for (int n = 0; n < 8; ++n) {
      int col = bn + wn * 128 + n * 16 + ar;
      float bb = b2[e * DIM + col];
#pragma unroll
      for (int m = 0; m < 4; ++m) {
        int rloc = wm * 64 + m * 16 + kg * 4;
#pragma unroll
        for (int r = 0; r < 4; ++r) {
          float w = swt[rloc + r];
          if (w != 0.f) {
            float v = (acc[m][n][r] + bb) * fabsf(w);
            atomicAdd(&out[(size_t)stok[rloc + r] * DIM + col], v);
          }
        }
      }
    }
  }
}

// ---------------- combine: out = part0 + part1 (streaming) ----------------
__global__ __launch_bounds__(256) void k_combine(const unsigned short* __restrict__ p0,
                                                 const unsigned short* __restrict__ p1,
                                                 float* __restrict__ out) {
  size_t i = ((size_t)blockIdx.x * 256 + threadIdx.x) * 8;
  int4 a = *(const int4*)(p0 + i);
  int4 b = *(const int4*)(p1 + i);
  unsigned int ua[4] = {(unsigned)a.x, (unsigned)a.y, (unsigned)a.z, (unsigned)a.w};
  unsigned int ub[4] = {(unsigned)b.x, (unsigned)b.y, (unsigned)b.z, (unsigned)b.w};
  float o[8];
#pragma unroll
  for (int q = 0; q < 4; ++q) {
    o[q * 2 + 0] = bf2f(ua[q] & 0xffffu) + bf2f(ub[q] & 0xffffu);
    o[q * 2 + 1] = bf2f(ua[q] >> 16)     + bf2f(ub[q] >> 16);
  }
  *(float4*)(out + i)     = *(float4*)&o[0];
  *(float4*)(out + i + 4) = *(float4*)&o[4];
}

extern "C" void kernel_launch(void* const* d_in, const int* in_sizes, int n_in,
                              void* d_out, int out_size, void* d_ws, size_t ws_size,
                              hipStream_t stream) {
  const float* x   = (const float*)d_in[0];
  const float* W1  = (const float*)d_in[1];
  const float* b1  = (const float*)d_in[2];
  const float* W2  = (const float*)d_in[3];
  const float* b2  = (const float*)d_in[4];
  const float* Wg1 = (const float*)d_in[5];
  const float* bg1 = (const float*)d_in[6];
  const float* Wg2 = (const float*)d_in[7];
  const float* bg2 = (const float*)d_in[8];
  float* out = (float*)d_out;                       // [N][768] then [N][8]
  float* gprob = out + (size_t)NTOK * DIM;

  char* ws = (char*)d_ws;
  size_t off = 0;
  auto alloc = [&](size_t bytes) { void* pp = ws + off; off += (bytes + 255) & ~(size_t)255; return pp; };
  unsigned short* xbf = (unsigned short*)alloc((size_t)NTOK * DIM * 2);
  unsigned short* w1t = (unsigned short*)alloc((size_t)NEXP * HID * DIM * 2);
  unsigned short* w2t = (unsigned short*)alloc((size_t)NEXP * DIM * HID * 2);
  float* hg = (float*)alloc((size_t)NTOK * HID * 4);
  int* cnt = (int*)alloc(NEXP * 32 * 4);            // 128B-padded counters
  int* lists = (int*)alloc((size_t)NEXP * NTOK * 4);
  float* wts = (float*)alloc((size_t)NEXP * NTOK * 4);
  unsigned short* part0 = (unsigned short*)alloc((size_t)NTOK * DIM * 2);
  unsigned short* part1 = (unsigned short*)alloc((size_t)NTOK * DIM * 2);
  bool store_mode = (off <= ws_size);

  // Gate scratch overlays part0 (written only by k_ffn2/k_combine, strictly after
  // every reader of these aliases in stream order). Fallback: dedicated allocs.
  unsigned short* wg1t;
  float* gs; int* rcnt; int* rlist;
  if (store_mode) {
    wg1t = part0;                                    // [0, 384KB)
    char* p0b = (char*)part0;
    gs    = (float*)(p0b + (1u << 20));              // [1MB, 2MB)
    rcnt  = (int*)(p0b + 9 * (1u << 18));            // 2.25MB
    rlist = (int*)(p0b + 10 * (1u << 18));           // [2.5MB, +128KB)
  } else {
    wg1t  = (unsigned short*)alloc((size_t)DIM * HID * 2);
    gs    = (float*)alloc((size_t)NTOK * 8 * 4);
    rcnt  = (int*)alloc(256);
    rlist = (int*)alloc((size_t)NTOK * 4);
  }

  // h (65536 compact rows x 256 bf16 = 32MB) reuses hg's 32MB (gate2a finishes first).
  unsigned short* h = (unsigned short*)hg;

  hipMemsetAsync(cnt, 0, NEXP * 32 * sizeof(int), stream);
  hipMemsetAsync(rcnt, 0, sizeof(int), stream);
  if (!store_mode)
    hipMemsetAsync(d_out, 0, (size_t)NTOK * DIM * sizeof(float), stream);

  k_cvt_x<<<(NTOK * DIM) / (256 * 8), 256, 0, stream>>>(x, xbf);
  k_tr<<<dim3(HID / 32, DIM / 32, 1), 256, 0, stream>>>(Wg1, wg1t, DIM, HID);   // -> wg1t[h][d]
  k_tr<<<dim3(HID / 32, DIM / 32, NEXP), 256, 0, stream>>>(W1, w1t, DIM, HID);  // -> w1t[e][h][d]
  k_tr<<<dim3(DIM / 32, HID / 32, NEXP), 256, 0, stream>>>(W2, w2t, HID, DIM);  // -> w2t[e][d][h]
  k_gmfma<<<dim3(NTOK / 128, HID / 128), 256, 0, stream>>>(xbf, wg1t, bg1, hg);
  k_gate2a<<<NTOK / 256, 256, 0, stream>>>(hg, Wg2, bg2, gs, rcnt, rlist);
  k_rescue<<<2048, 256, 0, stream>>>(x, Wg1, bg1, Wg2, bg2, rcnt, rlist, gs);
  k_gate2b<<<NTOK / 256, 256, 0, stream>>>(gs, gprob, cnt, lists, wts);
  k_ffn1<<<dim3(NTOK / 128, 2, NEXP), 256, 0, stream>>>(xbf, w1t, b1, cnt, lists, h);
  if (store_mode) {
    k_ffn2<true><<<dim3(NTOK / 128, 3, NEXP), 256, 0, stream>>>(h, w2t, b2, cnt, lists, wts, part0, part1, out);
    k_combine<<<(NTOK * DIM) / (256 * 8), 256, 0, stream>>>(part0, part1, out);
  } else {
    k_ffn2<false><<<dim3(NTOK / 128, 3, NEXP), 256, 0, stream>>>(h, w2t, b2, cnt, lists, wts, part0, part1, out);
  }
}

// Round 14
// 272.270 us; speedup vs baseline: 1.4854x; 1.4177x over previous
//
#include <hip/hip_runtime.h>
#include <hip/hip_bf16.h>
#include <stdint.h>

#define NTOK 32768
#define DIM  768
#define HID  256
#define NEXP 8
#define PADC 144   // repack-tile column pad: conflict-reduced epilogue writes

typedef float f32x4 __attribute__((ext_vector_type(4)));
typedef short s16x8 __attribute__((ext_vector_type(8)));

__device__ __forceinline__ unsigned short f2bf(float f) {
  union { float f; unsigned int u; } c; c.f = f;
  unsigned int r = c.u + 0x7fffu + ((c.u >> 16) & 1u);
  return (unsigned short)(r >> 16);
}

__device__ __forceinline__ float bf2f(unsigned int u) {
  union { unsigned int x; float f; } c; c.x = u << 16; return c.f;
}

// async global -> LDS, 16B per lane. LDS dest is wave-uniform base + lane*16.
__device__ __forceinline__ void gload_lds16(const unsigned short* g, unsigned short* l) {
  __builtin_amdgcn_global_load_lds((const __attribute__((address_space(1))) void*)g,
                                   (__attribute__((address_space(3))) void*)l, 16, 0, 0);
}

// ---------------- x fp32 -> bf16 hi + lo ----------------
__global__ __launch_bounds__(256) void k_cvt_x(const float* __restrict__ x,
                                               unsigned short* __restrict__ xbf,
                                               unsigned short* __restrict__ xlo) {
  int i = (blockIdx.x * 256 + threadIdx.x) * 8;
  float4 a = *(const float4*)(x + i);
  float4 b = *(const float4*)(x + i + 4);
  unsigned short h[8];
  float f[8] = {a.x, a.y, a.z, a.w, b.x, b.y, b.z, b.w};
  unsigned short lo[8];
#pragma unroll
  for (int q = 0; q < 8; ++q) {
    h[q] = f2bf(f[q]);
    lo[q] = f2bf(f[q] - bf2f(h[q]));
  }
  int4 vh, vl;
  vh.x = (int)((unsigned)h[0] | ((unsigned)h[1] << 16));
  vh.y = (int)((unsigned)h[2] | ((unsigned)h[3] << 16));
  vh.z = (int)((unsigned)h[4] | ((unsigned)h[5] << 16));
  vh.w = (int)((unsigned)h[6] | ((unsigned)h[7] << 16));
  vl.x = (int)((unsigned)lo[0] | ((unsigned)lo[1] << 16));
  vl.y = (int)((unsigned)lo[2] | ((unsigned)lo[3] << 16));
  vl.z = (int)((unsigned)lo[4] | ((unsigned)lo[5] << 16));
  vl.w = (int)((unsigned)lo[6] | ((unsigned)lo[7] << 16));
  *(int4*)(xbf + i) = vh;
  *(int4*)(xlo + i) = vl;
}

// ---------------- fp32 [R][C] -> bf16 [C][R] transpose via LDS tile ----------------
__global__ __launch_bounds__(256) void k_tr(const float* __restrict__ in,
                                            unsigned short* __restrict__ outp,
                                            int R, int C) {
  __shared__ float tile[32][33];
  int e = blockIdx.z;
  const float* ip = in + (size_t)e * R * C;
  unsigned short* op = outp + (size_t)e * R * C;
  int tx = threadIdx.x & 31, ty = threadIdx.x >> 5;  // 32x8
  int r0 = blockIdx.y * 32, c0 = blockIdx.x * 32;
#pragma unroll
  for (int i = 0; i < 4; ++i)
    tile[ty + i * 8][tx] = ip[(size_t)(r0 + ty + i * 8) * C + c0 + tx];
  __syncthreads();
#pragma unroll
  for (int i = 0; i < 4; ++i)
    op[(size_t)(c0 + ty + i * 8) * R + r0 + tx] = f2bf(tile[tx][ty + i * 8]);
}

// ---------------- fp32 [R][C] -> bf16 [C][R] transpose, hi+lo split ----------------
__global__ __launch_bounds__(256) void k_tr2(const float* __restrict__ in,
                                             unsigned short* __restrict__ ohi,
                                             unsigned short* __restrict__ olo,
                                             int R, int C) {
  __shared__ float tile[32][33];
  int tx = threadIdx.x & 31, ty = threadIdx.x >> 5;
  int r0 = blockIdx.y * 32, c0 = blockIdx.x * 32;
#pragma unroll
  for (int i = 0; i < 4; ++i)
    tile[ty + i * 8][tx] = in[(size_t)(r0 + ty + i * 8) * C + c0 + tx];
  __syncthreads();
#pragma unroll
  for (int i = 0; i < 4; ++i) {
    float v = tile[tx][ty + i * 8];
    unsigned short h = f2bf(v);
    size_t o = (size_t)(c0 + ty + i * 8) * R + r0 + tx;
    ohi[o] = h;
    olo[o] = f2bf(v - bf2f(h));
  }
}

// ---------------- gate layer 1, split-bf16 MFMA: hg = relu(x @ Wg1 + bg1) ----------------
// x = xhi + xlo, Wg1^T = whi + wlo (bf16 pairs). S ~= xhi@whi + xhi@wlo + xlo@whi, fp32 acc.
__global__ __launch_bounds__(256) void k_gmfma(const unsigned short* __restrict__ xhi,
                                               const unsigned short* __restrict__ xlo,
                                               const unsigned short* __restrict__ whi,
                                               const unsigned short* __restrict__ wlo,
                                               const float* __restrict__ bg1,
                                               float* __restrict__ hg) {
  int bm = blockIdx.x * 128;
  int bn = blockIdx.y * 128;

  __shared__ __align__(16) unsigned short Ah[128 * 64];
  __shared__ __align__(16) unsigned short Al[128 * 64];
  __shared__ __align__(16) unsigned short Bh[128 * 64];
  __shared__ __align__(16) unsigned short Bl[128 * 64];

  int tid = threadIdx.x;
  int lane = tid & 63;
  int wid = tid >> 6;
  int wm = wid >> 1, wn = wid & 1;
  int ar = lane & 15, kg = lane >> 4;

  const unsigned short *sah[4], *sal[4], *sbh[4], *sbl[4];
  unsigned short *dA[4], *dAl[4], *dB[4], *dBl[4];
#pragma unroll
  for (int i = 0; i < 4; ++i) {
    int cb0 = i * 256 + wid * 64;        // wave-uniform chunk base
    int ci = cb0 + lane;
    int row = ci >> 3;
    int cb = (ci & 7) ^ (row & 7);       // inverse-swizzled source chunk
    size_t aoff = (size_t)(bm + row) * DIM + cb * 8;
    size_t boff = (size_t)(bn + row) * DIM + cb * 8;
    sah[i] = xhi + aoff; sal[i] = xlo + aoff;
    sbh[i] = whi + boff; sbl[i] = wlo + boff;
    dA[i] = &Ah[cb0 * 8]; dAl[i] = &Al[cb0 * 8];
    dB[i] = &Bh[cb0 * 8]; dBl[i] = &Bl[cb0 * 8];
  }

  f32x4 acc[4][4] = {};

  for (int kt = 0; kt < DIM / 64; ++kt) {
#pragma unroll
    for (int i = 0; i < 4; ++i) {
      gload_lds16(sah[i] + kt * 64, dA[i]);
      gload_lds16(sal[i] + kt * 64, dAl[i]);
      gload_lds16(sbh[i] + kt * 64, dB[i]);
      gload_lds16(sbl[i] + kt * 64, dBl[i]);
    }
    __syncthreads();
#pragma unroll
    for (int ks = 0; ks < 2; ++ks) {
      int kc = ks * 4 + kg;
      s16x8 ah[4], al[4], bh[4], bl[4];
#pragma unroll
      for (int m = 0; m < 4; ++m) {
        int row = wm * 64 + m * 16 + ar;
        int off = row * 64 + ((kc ^ (row & 7)) * 8);
        ah[m] = *(const s16x8*)&Ah[off];
        al[m] = *(const s16x8*)&Al[off];
      }
#pragma unroll
      for (int n = 0; n < 4; ++n) {
        int row = wn * 64 + n * 16 + ar;
        int off = row * 64 + ((kc ^ (row & 7)) * 8);
        bh[n] = *(const s16x8*)&Bh[off];
        bl[n] = *(const s16x8*)&Bl[off];
      }
#pragma unroll
      for (int m = 0; m < 4; ++m)
#pragma unroll
        for (int n = 0; n < 4; ++n) {
          acc[m][n] = __builtin_amdgcn_mfma_f32_16x16x32_bf16(ah[m], bh[n], acc[m][n], 0, 0, 0);
          acc[m][n] = __builtin_amdgcn_mfma_f32_16x16x32_bf16(ah[m], bl[n], acc[m][n], 0, 0, 0);
          acc[m][n] = __builtin_amdgcn_mfma_f32_16x16x32_bf16(al[m], bh[n], acc[m][n], 0, 0, 0);
        }
    }
    __syncthreads();
  }

  // bias + relu -> hg fp32
#pragma unroll
  for (int n = 0; n < 4; ++n) {
    int col = bn + wn * 64 + n * 16 + ar;
    float bb = bg1[col];
#pragma unroll
    for (int m = 0; m < 4; ++m) {
      int rbase = bm + wm * 64 + m * 16 + kg * 4;
#pragma unroll
      for (int r = 0; r < 4; ++r)
        hg[(size_t)(rbase + r) * HID + col] = fmaxf(acc[m][n][r] + bb, 0.f);
    }
  }
}

// ---------------- gate 2a: scores from hg -> gs; flag near-ties for fp32 rescue ----------------
__global__ __launch_bounds__(256) void k_gate2a(const float* __restrict__ hg,
                                                const float* __restrict__ wg2,
                                                const float* __restrict__ bg2,
                                                float* __restrict__ gs,
                                                int* __restrict__ rcnt,
                                                int* __restrict__ rlist) {
  int tok = blockIdx.x * 256 + threadIdx.x;
  const float* hrow = hg + (size_t)tok * HID;

  float s[8];
#pragma unroll
  for (int e = 0; e < 8; ++e) s[e] = bg2[e];
#pragma unroll 8
  for (int j = 0; j < 64; ++j) {
    f32x4 hv = *(const f32x4*)(hrow + j * 4);
#pragma unroll
    for (int i = 0; i < 4; ++i) {
      const float* wr = wg2 + (j * 4 + i) * 8;
#pragma unroll
      for (int e = 0; e < 8; ++e) s[e] += hv[i] * wr[e];
    }
  }

  f32x4 o0 = {s[0], s[1], s[2], s[3]};
  f32x4 o1 = {s[4], s[5], s[6], s[7]};
  *(f32x4*)&gs[(size_t)tok * 8] = o0;
  *(f32x4*)&gs[(size_t)tok * 8 + 4] = o1;

  // top-3 scan; split-bf16 score error vs np is ~1e-5 worst-case. If the
  // rank2/rank3 gap is under 1e-3 (100x margin) recompute this token in fp32.
  float m1 = -3e38f, m2 = -3e38f, m3 = -3e38f;
#pragma unroll
  for (int e = 0; e < 8; ++e) {
    float v = s[e];
    if (v > m1)      { m3 = m2; m2 = m1; m1 = v; }
    else if (v > m2) { m3 = m2; m2 = v; }
    else if (v > m3) { m3 = v; }
  }
  if (m2 - m3 < 1e-3f) {
    int i = atomicAdd(rcnt, 1);
    rlist[i] = tok;
  }
}

// ---------------- rescue: exact fp32 gate recompute for flagged tokens ----------------
// Block-per-token (grid-stride over 2048). 8 independent accumulators + unroll
// keep ~32 loads in flight; dependent-FMA chain is 96 deep, not 768.
__global__ __launch_bounds__(256) void k_rescue(const float* __restrict__ x,
                                                const float* __restrict__ wg1,
                                                const float* __restrict__ bg1,
                                                const float* __restrict__ wg2,
                                                const float* __restrict__ bg2,
                                                const int* __restrict__ rcnt,
                                                const int* __restrict__ rlist,
                                                float* __restrict__ gs) {
  __shared__ float xs[DIM];
  __shared__ float ps[4][8];
  int n = rcnt[0];
  int tid = threadIdx.x;
  int lane = tid & 63, wid = tid >> 6;
  for (int idx = blockIdx.x; idx < n; idx += 2048) {
    int tok = rlist[idx];
    __syncthreads();  // protect xs/ps reuse across iterations
#pragma unroll
    for (int q = 0; q < 3; ++q) xs[tid + q * 256] = x[(size_t)tok * DIM + tid + q * 256];
    __syncthreads();
    const float* wcol = wg1 + tid;               // tid = hidden unit (HID==256)
    float pa[8] = {};
#pragma unroll 4
    for (int k0 = 0; k0 < DIM; k0 += 8) {
#pragma unroll
      for (int q = 0; q < 8; ++q)
        pa[q] = fmaf(xs[k0 + q], wcol[(size_t)(k0 + q) * HID], pa[q]);
    }
    float acc = bg1[tid] +
                (((pa[0] + pa[1]) + (pa[2] + pa[3])) + ((pa[4] + pa[5]) + (pa[6] + pa[7])));
    float hj = fmaxf(acc, 0.f);
    float p[8];
#pragma unroll
    for (int e = 0; e < 8; ++e) p[e] = hj * wg2[tid * 8 + e];
#pragma unroll
    for (int off = 32; off >= 1; off >>= 1) {
#pragma unroll
      for (int e = 0; e < 8; ++e) p[e] += __shfl_xor(p[e], off);
    }
    if (lane == 0) {
#pragma unroll
      for (int e = 0; e < 8; ++e) ps[wid][e] = p[e];
    }
    __syncthreads();
    if (tid < 8)
      gs[(size_t)tok * 8 + tid] = bg2[tid] + ps[0][tid] + ps[1][tid] + ps[2][tid] + ps[3][tid];
  }
}

// ---------------- gate 2b: softmax + top2 + routing lists from gs ----------------
// wts sign-encodes rank: +w for top-1 expert entry, -w for top-2 entry.
__global__ __launch_bounds__(256) void k_gate2b(const float* __restrict__ gs,
                                                float* __restrict__ gprob,
                                                int* __restrict__ cnt,     // stride 32
                                                int* __restrict__ lists,
                                                float* __restrict__ wts) {
  __shared__ int lcnt[8];
  __shared__ int sbase[8];
  __shared__ int se1[256], se2[256], sp1[256], sp2[256];
  __shared__ float sw1[256], sw2[256];
  int tid = threadIdx.x;
  if (tid < 8) lcnt[tid] = 0;
  __syncthreads();

  int tok = blockIdx.x * 256 + tid;
  f32x4 s0v = *(const f32x4*)&gs[(size_t)tok * 8];
  f32x4 s1v = *(const f32x4*)&gs[(size_t)tok * 8 + 4];
  float s[8] = {s0v[0], s0v[1], s0v[2], s0v[3], s1v[0], s1v[1], s1v[2], s1v[3]};

  float m = s[0];
#pragma unroll
  for (int e = 1; e < 8; ++e) m = fmaxf(m, s[e]);
  float p[8]; float sum = 0.f;
#pragma unroll
  for (int e = 0; e < 8; ++e) { p[e] = expf(s[e] - m); sum += p[e]; }
  float inv = 1.f / sum;
#pragma unroll
  for (int e = 0; e < 8; ++e) p[e] *= inv;

  f32x4 o0 = {p[0], p[1], p[2], p[3]};
  f32x4 o1 = {p[4], p[5], p[6], p[7]};
  *(f32x4*)&gprob[(size_t)tok * 8] = o0;
  *(f32x4*)&gprob[(size_t)tok * 8 + 4] = o1;

  int e1 = 0; float p1 = p[0];
#pragma unroll
  for (int e = 1; e < 8; ++e) if (p[e] > p1) { p1 = p[e]; e1 = e; }
  int e2 = -1; float p2 = -1.f;
#pragma unroll
  for (int e = 0; e < 8; ++e) if (e != e1 && p[e] > p2) { p2 = p[e]; e2 = e; }
  float rinv = 1.f / (p1 + p2);

  int pos1 = atomicAdd(&lcnt[e1], 1);
  int pos2 = atomicAdd(&lcnt[e2], 1);
  se1[tid] = e1; sp1[tid] = pos1; sw1[tid] = p1 * rinv;
  se2[tid] = e2; sp2[tid] = pos2; sw2[tid] = p2 * rinv;
  __syncthreads();

  if (tid < 8) sbase[tid] = atomicAdd(&cnt[tid * 32], lcnt[tid]);
  __syncthreads();

  int a1i = sbase[se1[tid]] + sp1[tid];
  lists[se1[tid] * NTOK + a1i] = tok; wts[se1[tid] * NTOK + a1i] = sw1[tid];   // rank0: +w
  int a2i = sbase[se2[tid]] + sp2[tid];
  lists[se2[tid] * NTOK + a2i] = tok; wts[se2[tid] * NTOK + a2i] = -sw2[tid];  // rank1: -w
}

// ---------------- expert layer 1 GEMM: h = relu(x_gathered @ W1^T + b1) ----------------
// 1D grid with XCD-aware decode: both bn panels of one row-tile land on one XCD
// (consecutive XCD-local ids) so the gathered A-tile is re-read from L2, not L3.
__global__ __launch_bounds__(256) void k_ffn1(const unsigned short* __restrict__ xbf,
                                              const unsigned short* __restrict__ w1t,
                                              const float* __restrict__ b1,
                                              const int* __restrict__ cnt,
                                              const int* __restrict__ lists,
                                              unsigned short* __restrict__ h) {
  int id = blockIdx.x;
  int xcd = id & 7, local = id >> 3;
  int bny = local & 1;
  int r2 = local >> 1;
  int xh = r2 & 31, e = r2 >> 5;
  int row0 = ((xh << 3) | xcd) * 128;
  int bn = bny * 128;

  int c = cnt[e * 32];
  if (row0 >= c) return;
  int pfx = 0;
#pragma unroll
  for (int j = 0; j < 8; ++j) if (j < e) pfx += cnt[j * 32];

  __shared__ __align__(16) unsigned short smem[128 * PADC];  // staging (32KB) U repack tile (36KB)
  __shared__ int stok[128];
  unsigned short* As = smem;
  unsigned short* Bs = smem + 128 * 64;

  int tid = threadIdx.x;
  int lane = tid & 63;
  int wid = tid >> 6;
  int wm = wid >> 1, wn = wid & 1;
  int ar = lane & 15, kg = lane >> 4;

  if (tid < 128) stok[tid] = lists[e * NTOK + min(row0 + tid, c - 1)];
  __syncthreads();

  const unsigned short* asrc[4];
  const unsigned short* bsrc[4];
  unsigned short* ldsA[4];
  unsigned short* ldsB[4];
#pragma unroll
  for (int i = 0; i < 4; ++i) {
    int cb0 = i * 256 + wid * 64;        // wave-uniform chunk base
    int ci = cb0 + lane;
    int row = ci >> 3;
    int cb = (ci & 7) ^ (row & 7);       // inverse-swizzled source chunk
    asrc[i] = xbf + (size_t)stok[row] * DIM + cb * 8;
    bsrc[i] = w1t + ((size_t)e * HID + bn + row) * DIM + cb * 8;
    ldsA[i] = &As[cb0 * 8];
    ldsB[i] = &Bs[cb0 * 8];
  }

  f32x4 acc[4][4] = {};

  for (int kt = 0; kt < DIM / 64; ++kt) {
#pragma unroll
    for (int i = 0; i < 4; ++i) {
      gload_lds16(asrc[i] + kt * 64, ldsA[i]);
      gload_lds16(bsrc[i] + kt * 64, ldsB[i]);
    }
    __syncthreads();
#pragma unroll
    for (int ks = 0; ks < 2; ++ks) {
      int kc = ks * 4 + kg;
      s16x8 a[4], b[4];
#pragma unroll
      for (int m = 0; m < 4; ++m) {
        int row = wm * 64 + m * 16 + ar;
        a[m] = *(const s16x8*)&As[row * 64 + ((kc ^ (row & 7)) * 8)];
      }
#pragma unroll
      for (int n = 0; n < 4; ++n) {
        int row = wn * 64 + n * 16 + ar;
        b[n] = *(const s16x8*)&Bs[row * 64 + ((kc ^ (row & 7)) * 8)];
      }
#pragma unroll
      for (int m = 0; m < 4; ++m)
#pragma unroll
        for (int n = 0; n < 4; ++n)
          acc[m][n] = __builtin_amdgcn_mfma_f32_16x16x32_bf16(a[m], b[n], acc[m][n], 0, 0, 0);
    }
    __syncthreads();
  }

  // bias + relu -> LDS repack tile -> coalesced 16B stores (compact rows)
#pragma unroll
  for (int n = 0; n < 4; ++n) {
    int col = wn * 64 + n * 16 + ar;             // within-tile col
    float bb = b1[e * HID + bn + col];
#pragma unroll
    for (int m = 0; m < 4; ++m) {
      int rloc = wm * 64 + m * 16 + kg * 4;
#pragma unroll
      for (int r = 0; r < 4; ++r)
        smem[(rloc + r) * PADC + col] = f2bf(fmaxf(acc[m][n][r] + bb, 0.f));
    }
  }
  __syncthreads();
  int hbase = pfx + row0;
#pragma unroll
  for (int q = 0; q < 8; ++q) {
    int ci = tid + q * 256;
    int row = ci >> 4, ch = ci & 15;
    if (row0 + row < c) {
      int4 v = *(const int4*)&smem[row * PADC + ch * 8];
      *(int4*)&h[(size_t)(hbase + row) * HID + bn + ch * 8] = v;
    }
  }
}

// ---------------- expert layer 2 GEMM + rank-split partial store (or atomic fallback) ----------------
// 1D grid with XCD-aware decode: all 6 bn panels of one row-tile land on one XCD
// (consecutive XCD-local ids) so the A-tile (h rows) is re-read from L2, not L3.
template <bool STORE_PART>
__global__ __launch_bounds__(256) void k_ffn2(const unsigned short* __restrict__ h,
                                              const unsigned short* __restrict__ w2t,
                                              const float* __restrict__ b2,
                                              const int* __restrict__ cnt,
                                              const int* __restrict__ lists,
                                              const float* __restrict__ wts,
                                              unsigned short* __restrict__ part0,
                                              unsigned short* __restrict__ part1,
                                              float* __restrict__ out) {
  int id = blockIdx.x;
  int xcd = id & 7, local = id >> 3;
  int bny = local % 6;
  int r2 = local / 6;
  int xh = r2 & 31, e = r2 >> 5;
  int row0 = ((xh << 3) | xcd) * 128;
  int bn = bny * 128;

  int c = cnt[e * 32];
  if (row0 >= c) return;
  int pfx = 0;
#pragma unroll
  for (int j = 0; j < 8; ++j) if (j < e) pfx += cnt[j * 32];

  __shared__ __align__(16) unsigned short smem[128 * PADC];  // staging (32KB) U repack tile (36KB)
  __shared__ int stok[128];
  __shared__ float swt[128];
  unsigned short* As = smem;
  unsigned short* Bs = smem + 128 * 64;

  int tid = threadIdx.x;
  int lane = tid & 63;
  int wid = tid >> 6;
  int wm = wid >> 1, wn = wid & 1;
  int ar = lane & 15, kg = lane >> 4;

  if (tid < 128) {
    int r = row0 + tid;
    stok[tid] = (r < c) ? lists[e * NTOK + r] : 0;
    swt[tid]  = (r < c) ? wts[e * NTOK + r] : 0.f;
  }
  __syncthreads();

  const unsigned short* asrc[4];
  const unsigned short* bsrc[4];
  unsigned short* ldsA[4];
  unsigned short* ldsB[4];
#pragma unroll
  for (int i = 0; i < 4; ++i) {
    int cb0 = i * 256 + wid * 64;
    int ci = cb0 + lane;
    int row = ci >> 3;
    int cb = (ci & 7) ^ (row & 7);
    asrc[i] = h + (size_t)(pfx + row0 + row) * HID + cb * 8;
    bsrc[i] = w2t + ((size_t)e * DIM + bn + row) * HID + cb * 8;
    ldsA[i] = &As[cb0 * 8];
    ldsB[i] = &Bs[cb0 * 8];
  }

  f32x4 acc[4][4] = {};

  for (int kt = 0; kt < HID / 64; ++kt) {
#pragma unroll
    for (int i = 0; i < 4; ++i) {
      gload_lds16(asrc[i] + kt * 64, ldsA[i]);
      gload_lds16(bsrc[i] + kt * 64, ldsB[i]);
    }
    __syncthreads();
#pragma unroll
    for (int ks = 0; ks < 2; ++ks) {
      int kc = ks * 4 + kg;
      s16x8 a[4], b[4];
#pragma unroll
      for (int m = 0; m < 4; ++m) {
        int row = wm * 64 + m * 16 + ar;
        a[m] = *(const s16x8*)&As[row * 64 + ((kc ^ (row & 7)) * 8)];
      }
#pragma unroll
      for (int n = 0; n < 4; ++n) {
        int row = wn * 64 + n * 16 + ar;
        b[n] = *(const s16x8*)&Bs[row * 64 + ((kc ^ (row & 7)) * 8)];
      }
#pragma unroll
      for (int m = 0; m < 4; ++m)
#pragma unroll
        for (int n = 0; n < 4; ++n)
          acc[m][n] = __builtin_amdgcn_mfma_f32_16x16x32_bf16(a[m], b[n], acc[m][n], 0, 0, 0);
    }
    __syncthreads();
  }

  if constexpr (STORE_PART) {
    // weighted bias epilogue -> LDS repack tile -> coalesced 16B stores per token row
#pragma unroll
    for (int n = 0; n < 4; ++n) {
      int col = wn * 64 + n * 16 + ar;           // within-tile col
      float bb = b2[e * DIM + bn + col];
#pragma unroll
      for (int m = 0; m < 4; ++m) {
        int rloc = wm * 64 + m * 16 + kg * 4;
#pragma unroll
        for (int r = 0; r < 4; ++r) {
          float w = swt[rloc + r];
          smem[(rloc + r) * PADC + col] = f2bf((acc[m][n][r] + bb) * fabsf(w));
        }
      }
    }
    __syncthreads();
#pragma unroll
    for (int q = 0; q < 8; ++q) {
      int ci = tid + q * 256;
      int row = ci >> 4, ch = ci & 15;
      float w = swt[row];
      if (w != 0.f) {
        unsigned short* dst = (w > 0.f) ? part0 : part1;
        int4 v = *(const int4*)&smem[row * PADC + ch * 8];
        *(int4*)&dst[(size_t)stok[row] * DIM + bn + ch * 8] = v;
      }
    }
  } else {
    // atomic fallback
#pragma unroll
    for (int n = 0; n < 4; ++n) {
      int col = bn + wn * 64 + n * 16 + ar;
      float bb = b2[e * DIM + col];
#pragma unroll
      for (int m = 0; m < 4; ++m) {
        int rloc = wm * 64 + m * 16 + kg * 4;
#pragma unroll
        for (int r = 0; r < 4; ++r) {
          float w = swt[rloc + r];
          if (w != 0.f) {
            float v = (acc[m][n][r] + bb) * fabsf(w);
            atomicAdd(&out[(size_t)stok[rloc + r] * DIM + col], v);
          }
        }
      }
    }
  }
}

// ---------------- combine: out = part0 + part1 (streaming) ----------------
__global__ __launch_bounds__(256) void k_combine(const unsigned short* __restrict__ p0,
                                                 const unsigned short* __restrict__ p1,
                                                 float* __restrict__ out) {
  size_t i = ((size_t)blockIdx.x * 256 + threadIdx.x) * 8;
  int4 a = *(const int4*)(p0 + i);
  int4 b = *(const int4*)(p1 + i);
  unsigned int ua[4] = {(unsigned)a.x, (unsigned)a.y, (unsigned)a.z, (unsigned)a.w};
  unsigned int ub[4] = {(unsigned)b.x, (unsigned)b.y, (unsigned)b.z, (unsigned)b.w};
  float o[8];
#pragma unroll
  for (int q = 0; q < 4; ++q) {
    o[q * 2 + 0] = bf2f(ua[q] & 0xffffu) + bf2f(ub[q] & 0xffffu);
    o[q * 2 + 1] = bf2f(ua[q] >> 16)     + bf2f(ub[q] >> 16);
  }
  *(float4*)(out + i)     = *(float4*)&o[0];
  *(float4*)(out + i + 4) = *(float4*)&o[4];
}

extern "C" void kernel_launch(void* const* d_in, const int* in_sizes, int n_in,
                              void* d_out, int out_size, void* d_ws, size_t ws_size,
                              hipStream_t stream) {
  const float* x   = (const float*)d_in[0];
  const float* W1  = (const float*)d_in[1];
  const float* b1  = (const float*)d_in[2];
  const float* W2  = (const float*)d_in[3];
  const float* b2  = (const float*)d_in[4];
  const float* Wg1 = (const float*)d_in[5];
  const float* bg1 = (const float*)d_in[6];
  const float* Wg2 = (const float*)d_in[7];
  const float* bg2 = (const float*)d_in[8];
  float* out = (float*)d_out;                       // [N][768] then [N][8]
  float* gprob = out + (size_t)NTOK * DIM;

  char* ws = (char*)d_ws;
  size_t off = 0;
  auto alloc = [&](size_t bytes) { void* pp = ws + off; off += (bytes + 255) & ~(size_t)255; return pp; };
  unsigned short* xbf = (unsigned short*)alloc((size_t)NTOK * DIM * 2);
  unsigned short* w1t = (unsigned short*)alloc((size_t)NEXP * HID * DIM * 2);
  unsigned short* w2t = (unsigned short*)alloc((size_t)NEXP * DIM * HID * 2);
  float* hg = (float*)alloc((size_t)NTOK * HID * 4);
  int* cnt = (int*)alloc(NEXP * 32 * 4);            // 128B-padded counters
  int* lists = (int*)alloc((size_t)NEXP * NTOK * 4);
  float* wts = (float*)alloc((size_t)NEXP * NTOK * 4);
  unsigned short* part0 = (unsigned short*)alloc((size_t)NTOK * DIM * 2);
  unsigned short* part1 = (unsigned short*)alloc((size_t)NTOK * DIM * 2);
  bool store_mode = (off <= ws_size);

  // Gate scratch. In store_mode it overlays part0/part1 interiors: those are
  // written only by k_ffn2/k_combine, which run strictly AFTER every reader
  // of these aliases (stream order serializes). Fallback: dedicated allocs.
  unsigned short *xlo, *wg1thi, *wg1tlo;
  float* gs; int* rcnt; int* rlist;
  if (store_mode) {
    xlo = part1;
    wg1thi = part0;                                  // [0, 768KB)
    wg1tlo = part0 + (size_t)DIM * HID;
    char* p0b = (char*)part0;
    gs    = (float*)(p0b + (1u << 20));              // [1MB, 2MB)
    rcnt  = (int*)(p0b + 9 * (1u << 18));            // 2.25MB
    rlist = (int*)(p0b + 10 * (1u << 18));           // [2.5MB, +128KB)
  } else {
    xlo    = (unsigned short*)alloc((size_t)NTOK * DIM * 2);
    wg1thi = (unsigned short*)alloc((size_t)DIM * HID * 2);
    wg1tlo = (unsigned short*)alloc((size_t)DIM * HID * 2);
    gs     = (float*)alloc((size_t)NTOK * 8 * 4);
    rcnt   = (int*)alloc(256);
    rlist  = (int*)alloc((size_t)NTOK * 4);
  }

  // h (65536 compact rows x 256 bf16 = 32MB) reuses hg's 32MB (gate2a finishes first).
  unsigned short* h = (unsigned short*)hg;

  hipMemsetAsync(cnt, 0, NEXP * 32 * sizeof(int), stream);
  hipMemsetAsync(rcnt, 0, sizeof(int), stream);
  if (!store_mode)
    hipMemsetAsync(d_out, 0, (size_t)NTOK * DIM * sizeof(float), stream);

  k_cvt_x<<<(NTOK * DIM) / (256 * 8), 256, 0, stream>>>(x, xbf, xlo);
  k_tr2<<<dim3(HID / 32, DIM / 32), 256, 0, stream>>>(Wg1, wg1thi, wg1tlo, DIM, HID); // -> [h][d] hi/lo
  k_tr<<<dim3(HID / 32, DIM / 32, NEXP), 256, 0, stream>>>(W1, w1t, DIM, HID);  // -> w1t[e][h][d]
  k_tr<<<dim3(DIM / 32, HID / 32, NEXP), 256, 0, stream>>>(W2, w2t, HID, DIM);  // -> w2t[e][d][h]
  k_gmfma<<<dim3(NTOK / 128, HID / 128), 256, 0, stream>>>(xbf, xlo, wg1thi, wg1tlo, bg1, hg);
  k_gate2a<<<NTOK / 256, 256, 0, stream>>>(hg, Wg2, bg2, gs, rcnt, rlist);
  k_rescue<<<2048, 256, 0, stream>>>(x, Wg1, bg1, Wg2, bg2, rcnt, rlist, gs);
  k_gate2b<<<NTOK / 256, 256, 0, stream>>>(gs, gprob, cnt, lists, wts);
  k_ffn1<<<(NTOK / 128) * 2 * NEXP, 256, 0, stream>>>(xbf, w1t, b1, cnt, lists, h);
  if (store_mode) {
    k_ffn2<true><<<(NTOK / 128) * 6 * NEXP, 256, 0, stream>>>(h, w2t, b2, cnt, lists, wts, part0, part1, out);
    k_combine<<<(NTOK * DIM) / (256 * 8), 256, 0, stream>>>(part0, part1, out);
  } else {
    k_ffn2<false><<<(NTOK / 128) * 6 * NEXP, 256, 0, stream>>>(h, w2t, b2, cnt, lists, wts, part0, part1, out);
  }
}

// Round 15
// 259.673 us; speedup vs baseline: 1.5574x; 1.0485x over previous
//
#include <hip/hip_runtime.h>
#include <hip/hip_bf16.h>
#include <stdint.h>

#define NTOK 32768
#define DIM  768
#define HID  256
#define NEXP 8
#define PADC 144   // repack-tile column pad: conflict-reduced epilogue writes

typedef float f32x4 __attribute__((ext_vector_type(4)));
typedef short s16x8 __attribute__((ext_vector_type(8)));

__device__ __forceinline__ unsigned short f2bf(float f) {
  union { float f; unsigned int u; } c; c.f = f;
  unsigned int r = c.u + 0x7fffu + ((c.u >> 16) & 1u);
  return (unsigned short)(r >> 16);
}

__device__ __forceinline__ float bf2f(unsigned int u) {
  union { unsigned int x; float f; } c; c.x = u << 16; return c.f;
}

__device__ __forceinline__ unsigned short f2h(float f) {
  union { _Float16 h; unsigned short u; } c; c.h = (_Float16)f; return c.u;
}

// async global -> LDS, 16B per lane. LDS dest is wave-uniform base + lane*16.
__device__ __forceinline__ void gload_lds16(const unsigned short* g, unsigned short* l) {
  __builtin_amdgcn_global_load_lds((const __attribute__((address_space(1))) void*)g,
                                   (__attribute__((address_space(3))) void*)l, 16, 0, 0);
}

// ---------------- x fp32 -> bf16 (experts) + fp16 (gate) ----------------
__global__ __launch_bounds__(256) void k_cvt_x(const float* __restrict__ x,
                                               unsigned short* __restrict__ xbf,
                                               unsigned short* __restrict__ xf16) {
  int i = (blockIdx.x * 256 + threadIdx.x) * 8;
  float4 a = *(const float4*)(x + i);
  float4 b = *(const float4*)(x + i + 4);
  float f[8] = {a.x, a.y, a.z, a.w, b.x, b.y, b.z, b.w};
  unsigned short hb[8], hh[8];
#pragma unroll
  for (int q = 0; q < 8; ++q) { hb[q] = f2bf(f[q]); hh[q] = f2h(f[q]); }
  int4 vb, vh;
  vb.x = (int)((unsigned)hb[0] | ((unsigned)hb[1] << 16));
  vb.y = (int)((unsigned)hb[2] | ((unsigned)hb[3] << 16));
  vb.z = (int)((unsigned)hb[4] | ((unsigned)hb[5] << 16));
  vb.w = (int)((unsigned)hb[6] | ((unsigned)hb[7] << 16));
  vh.x = (int)((unsigned)hh[0] | ((unsigned)hh[1] << 16));
  vh.y = (int)((unsigned)hh[2] | ((unsigned)hh[3] << 16));
  vh.z = (int)((unsigned)hh[4] | ((unsigned)hh[5] << 16));
  vh.w = (int)((unsigned)hh[6] | ((unsigned)hh[7] << 16));
  *(int4*)(xbf + i) = vb;
  *(int4*)(xf16 + i) = vh;
}

// ---------------- fp32 [R][C] -> bf16 [C][R] transpose via LDS tile ----------------
__global__ __launch_bounds__(256) void k_tr(const float* __restrict__ in,
                                            unsigned short* __restrict__ outp,
                                            int R, int C) {
  __shared__ float tile[32][33];
  int e = blockIdx.z;
  const float* ip = in + (size_t)e * R * C;
  unsigned short* op = outp + (size_t)e * R * C;
  int tx = threadIdx.x & 31, ty = threadIdx.x >> 5;  // 32x8
  int r0 = blockIdx.y * 32, c0 = blockIdx.x * 32;
#pragma unroll
  for (int i = 0; i < 4; ++i)
    tile[ty + i * 8][tx] = ip[(size_t)(r0 + ty + i * 8) * C + c0 + tx];
  __syncthreads();
#pragma unroll
  for (int i = 0; i < 4; ++i)
    op[(size_t)(c0 + ty + i * 8) * R + r0 + tx] = f2bf(tile[tx][ty + i * 8]);
}

// ---------------- fp32 [R][C] -> fp16 [C][R] transpose via LDS tile ----------------
__global__ __launch_bounds__(256) void k_trh(const float* __restrict__ in,
                                             unsigned short* __restrict__ outp,
                                             int R, int C) {
  __shared__ float tile[32][33];
  int tx = threadIdx.x & 31, ty = threadIdx.x >> 5;
  int r0 = blockIdx.y * 32, c0 = blockIdx.x * 32;
#pragma unroll
  for (int i = 0; i < 4; ++i)
    tile[ty + i * 8][tx] = in[(size_t)(r0 + ty + i * 8) * C + c0 + tx];
  __syncthreads();
#pragma unroll
  for (int i = 0; i < 4; ++i)
    outp[(size_t)(c0 + ty + i * 8) * R + r0 + tx] = f2h(tile[tx][ty + i * 8]);
}

// ---------------- gate layer 1, fp16 MFMA: hg = relu(x @ Wg1 + bg1) ----------------
// fp16 (10-bit mantissa): score-gap error sigma ~6e-5, so the 1e-3 rescue
// threshold is a 16-sigma guard. Single MFMA pass, 2 staging buffers.
__global__ __launch_bounds__(256) void k_gmfma(const unsigned short* __restrict__ xh,
                                               const unsigned short* __restrict__ wh,
                                               const float* __restrict__ bg1,
                                               float* __restrict__ hg) {
  int bm = blockIdx.x * 128;
  int bn = blockIdx.y * 128;

  __shared__ __align__(16) unsigned short Ah[128 * 64];
  __shared__ __align__(16) unsigned short Bh[128 * 64];

  int tid = threadIdx.x;
  int lane = tid & 63;
  int wid = tid >> 6;
  int wm = wid >> 1, wn = wid & 1;
  int ar = lane & 15, kg = lane >> 4;

  const unsigned short *sah[4], *sbh[4];
  unsigned short *dA[4], *dB[4];
#pragma unroll
  for (int i = 0; i < 4; ++i) {
    int cb0 = i * 256 + wid * 64;        // wave-uniform chunk base
    int ci = cb0 + lane;
    int row = ci >> 3;
    int cb = (ci & 7) ^ (row & 7);       // inverse-swizzled source chunk
    sah[i] = xh + (size_t)(bm + row) * DIM + cb * 8;
    sbh[i] = wh + (size_t)(bn + row) * DIM + cb * 8;
    dA[i] = &Ah[cb0 * 8];
    dB[i] = &Bh[cb0 * 8];
  }

  f32x4 acc[4][4] = {};

  for (int kt = 0; kt < DIM / 64; ++kt) {
#pragma unroll
    for (int i = 0; i < 4; ++i) {
      gload_lds16(sah[i] + kt * 64, dA[i]);
      gload_lds16(sbh[i] + kt * 64, dB[i]);
    }
    __syncthreads();
#pragma unroll
    for (int ks = 0; ks < 2; ++ks) {
      int kc = ks * 4 + kg;
      s16x8 a[4], b[4];
#pragma unroll
      for (int m = 0; m < 4; ++m) {
        int row = wm * 64 + m * 16 + ar;
        a[m] = *(const s16x8*)&Ah[row * 64 + ((kc ^ (row & 7)) * 8)];
      }
#pragma unroll
      for (int n = 0; n < 4; ++n) {
        int row = wn * 64 + n * 16 + ar;
        b[n] = *(const s16x8*)&Bh[row * 64 + ((kc ^ (row & 7)) * 8)];
      }
#pragma unroll
      for (int m = 0; m < 4; ++m)
#pragma unroll
        for (int n = 0; n < 4; ++n)
          acc[m][n] = __builtin_amdgcn_mfma_f32_16x16x32_f16(a[m], b[n], acc[m][n], 0, 0, 0);
    }
    __syncthreads();
  }

  // bias + relu -> hg fp32
#pragma unroll
  for (int n = 0; n < 4; ++n) {
    int col = bn + wn * 64 + n * 16 + ar;
    float bb = bg1[col];
#pragma unroll
    for (int m = 0; m < 4; ++m) {
      int rbase = bm + wm * 64 + m * 16 + kg * 4;
#pragma unroll
      for (int r = 0; r < 4; ++r)
        hg[(size_t)(rbase + r) * HID + col] = fmaxf(acc[m][n][r] + bb, 0.f);
    }
  }
}

// ---------------- gate 2a: scores from hg -> gs; flag near-ties for fp32 rescue ----------------
__global__ __launch_bounds__(256) void k_gate2a(const float* __restrict__ hg,
                                                const float* __restrict__ wg2,
                                                const float* __restrict__ bg2,
                                                float* __restrict__ gs,
                                                int* __restrict__ rcnt,
                                                int* __restrict__ rlist) {
  int tok = blockIdx.x * 256 + threadIdx.x;
  const float* hrow = hg + (size_t)tok * HID;

  float s[8];
#pragma unroll
  for (int e = 0; e < 8; ++e) s[e] = bg2[e];
#pragma unroll 8
  for (int j = 0; j < 64; ++j) {
    f32x4 hv = *(const f32x4*)(hrow + j * 4);
#pragma unroll
    for (int i = 0; i < 4; ++i) {
      const float* wr = wg2 + (j * 4 + i) * 8;
#pragma unroll
      for (int e = 0; e < 8; ++e) s[e] += hv[i] * wr[e];
    }
  }

  f32x4 o0 = {s[0], s[1], s[2], s[3]};
  f32x4 o1 = {s[4], s[5], s[6], s[7]};
  *(f32x4*)&gs[(size_t)tok * 8] = o0;
  *(f32x4*)&gs[(size_t)tok * 8 + 4] = o1;

  // top-3 scan; fp16-gate score-gap error sigma ~6e-5. 1e-3 threshold = 16 sigma:
  // tokens outside the window cannot flip their top-2 set; inside -> exact fp32.
  float m1 = -3e38f, m2 = -3e38f, m3 = -3e38f;
#pragma unroll
  for (int e = 0; e < 8; ++e) {
    float v = s[e];
    if (v > m1)      { m3 = m2; m2 = m1; m1 = v; }
    else if (v > m2) { m3 = m2; m2 = v; }
    else if (v > m3) { m3 = v; }
  }
  if (m2 - m3 < 1e-3f) {
    int i = atomicAdd(rcnt, 1);
    rlist[i] = tok;
  }
}

// ---------------- rescue: exact fp32 gate recompute for flagged tokens ----------------
// Block-per-token (grid-stride over 2048). 8 independent accumulators + unroll
// keep ~32 loads in flight; dependent-FMA chain is 96 deep, not 768.
__global__ __launch_bounds__(256) void k_rescue(const float* __restrict__ x,
                                                const float* __restrict__ wg1,
                                                const float* __restrict__ bg1,
                                                const float* __restrict__ wg2,
                                                const float* __restrict__ bg2,
                                                const int* __restrict__ rcnt,
                                                const int* __restrict__ rlist,
                                                float* __restrict__ gs) {
  __shared__ float xs[DIM];
  __shared__ float ps[4][8];
  int n = rcnt[0];
  int tid = threadIdx.x;
  int lane = tid & 63, wid = tid >> 6;
  for (int idx = blockIdx.x; idx < n; idx += 2048) {
    int tok = rlist[idx];
    __syncthreads();  // protect xs/ps reuse across iterations
#pragma unroll
    for (int q = 0; q < 3; ++q) xs[tid + q * 256] = x[(size_t)tok * DIM + tid + q * 256];
    __syncthreads();
    const float* wcol = wg1 + tid;               // tid = hidden unit (HID==256)
    float pa[8] = {};
#pragma unroll 4
    for (int k0 = 0; k0 < DIM; k0 += 8) {
#pragma unroll
      for (int q = 0; q < 8; ++q)
        pa[q] = fmaf(xs[k0 + q], wcol[(size_t)(k0 + q) * HID], pa[q]);
    }
    float acc = bg1[tid] +
                (((pa[0] + pa[1]) + (pa[2] + pa[3])) + ((pa[4] + pa[5]) + (pa[6] + pa[7])));
    float hj = fmaxf(acc, 0.f);
    float p[8];
#pragma unroll
    for (int e = 0; e < 8; ++e) p[e] = hj * wg2[tid * 8 + e];
#pragma unroll
    for (int off = 32; off >= 1; off >>= 1) {
#pragma unroll
      for (int e = 0; e < 8; ++e) p[e] += __shfl_xor(p[e], off);
    }
    if (lane == 0) {
#pragma unroll
      for (int e = 0; e < 8; ++e) ps[wid][e] = p[e];
    }
    __syncthreads();
    if (tid < 8)
      gs[(size_t)tok * 8 + tid] = bg2[tid] + ps[0][tid] + ps[1][tid] + ps[2][tid] + ps[3][tid];
  }
}

// ---------------- gate 2b: softmax + top2 + routing lists from gs ----------------
// wts sign-encodes rank: +w for top-1 expert entry, -w for top-2 entry.
__global__ __launch_bounds__(256) void k_gate2b(const float* __restrict__ gs,
                                                float* __restrict__ gprob,
                                                int* __restrict__ cnt,     // stride 32
                                                int* __restrict__ lists,
                                                float* __restrict__ wts) {
  __shared__ int lcnt[8];
  __shared__ int sbase[8];
  __shared__ int se1[256], se2[256], sp1[256], sp2[256];
  __shared__ float sw1[256], sw2[256];
  int tid = threadIdx.x;
  if (tid < 8) lcnt[tid] = 0;
  __syncthreads();

  int tok = blockIdx.x * 256 + tid;
  f32x4 s0v = *(const f32x4*)&gs[(size_t)tok * 8];
  f32x4 s1v = *(const f32x4*)&gs[(size_t)tok * 8 + 4];
  float s[8] = {s0v[0], s0v[1], s0v[2], s0v[3], s1v[0], s1v[1], s1v[2], s1v[3]};

  float m = s[0];
#pragma unroll
  for (int e = 1; e < 8; ++e) m = fmaxf(m, s[e]);
  float p[8]; float sum = 0.f;
#pragma unroll
  for (int e = 0; e < 8; ++e) { p[e] = expf(s[e] - m); sum += p[e]; }
  float inv = 1.f / sum;
#pragma unroll
  for (int e = 0; e < 8; ++e) p[e] *= inv;

  f32x4 o0 = {p[0], p[1], p[2], p[3]};
  f32x4 o1 = {p[4], p[5], p[6], p[7]};
  *(f32x4*)&gprob[(size_t)tok * 8] = o0;
  *(f32x4*)&gprob[(size_t)tok * 8 + 4] = o1;

  int e1 = 0; float p1 = p[0];
#pragma unroll
  for (int e = 1; e < 8; ++e) if (p[e] > p1) { p1 = p[e]; e1 = e; }
  int e2 = -1; float p2 = -1.f;
#pragma unroll
  for (int e = 0; e < 8; ++e) if (e != e1 && p[e] > p2) { p2 = p[e]; e2 = e; }
  float rinv = 1.f / (p1 + p2);

  int pos1 = atomicAdd(&lcnt[e1], 1);
  int pos2 = atomicAdd(&lcnt[e2], 1);
  se1[tid] = e1; sp1[tid] = pos1; sw1[tid] = p1 * rinv;
  se2[tid] = e2; sp2[tid] = pos2; sw2[tid] = p2 * rinv;
  __syncthreads();

  if (tid < 8) sbase[tid] = atomicAdd(&cnt[tid * 32], lcnt[tid]);
  __syncthreads();

  int a1i = sbase[se1[tid]] + sp1[tid];
  lists[se1[tid] * NTOK + a1i] = tok; wts[se1[tid] * NTOK + a1i] = sw1[tid];   // rank0: +w
  int a2i = sbase[se2[tid]] + sp2[tid];
  lists[se2[tid] * NTOK + a2i] = tok; wts[se2[tid] * NTOK + a2i] = -sw2[tid];  // rank1: -w
}

// ---------------- expert layer 1 GEMM: h = relu(x_gathered @ W1^T + b1) ----------------
// 1D grid with XCD-aware decode: both bn panels of one row-tile land on one XCD
// (consecutive XCD-local ids) so the gathered A-tile is re-read from L2, not L3.
__global__ __launch_bounds__(256) void k_ffn1(const unsigned short* __restrict__ xbf,
                                              const unsigned short* __restrict__ w1t,
                                              const float* __restrict__ b1,
                                              const int* __restrict__ cnt,
                                              const int* __restrict__ lists,
                                              unsigned short* __restrict__ h) {
  int id = blockIdx.x;
  int xcd = id & 7, local = id >> 3;
  int bny = local & 1;
  int r2 = local >> 1;
  int xh = r2 & 31, e = r2 >> 5;
  int row0 = ((xh << 3) | xcd) * 128;
  int bn = bny * 128;

  int c = cnt[e * 32];
  if (row0 >= c) return;
  int pfx = 0;
#pragma unroll
  for (int j = 0; j < 8; ++j) if (j < e) pfx += cnt[j * 32];

  __shared__ __align__(16) unsigned short smem[128 * PADC];  // staging (32KB) U repack tile (36KB)
  __shared__ int stok[128];
  unsigned short* As = smem;
  unsigned short* Bs = smem + 128 * 64;

  int tid = threadIdx.x;
  int lane = tid & 63;
  int wid = tid >> 6;
  int wm = wid >> 1, wn = wid & 1;
  int ar = lane & 15, kg = lane >> 4;

  if (tid < 128) stok[tid] = lists[e * NTOK + min(row0 + tid, c - 1)];
  __syncthreads();

  const unsigned short* asrc[4];
  const unsigned short* bsrc[4];
  unsigned short* ldsA[4];
  unsigned short* ldsB[4];
#pragma unroll
  for (int i = 0; i < 4; ++i) {
    int cb0 = i * 256 + wid * 64;        // wave-uniform chunk base
    int ci = cb0 + lane;
    int row = ci >> 3;
    int cb = (ci & 7) ^ (row & 7);       // inverse-swizzled source chunk
    asrc[i] = xbf + (size_t)stok[row] * DIM + cb * 8;
    bsrc[i] = w1t + ((size_t)e * HID + bn + row) * DIM + cb * 8;
    ldsA[i] = &As[cb0 * 8];
    ldsB[i] = &Bs[cb0 * 8];
  }

  f32x4 acc[4][4] = {};

  for (int kt = 0; kt < DIM / 64; ++kt) {
#pragma unroll
    for (int i = 0; i < 4; ++i) {
      gload_lds16(asrc[i] + kt * 64, ldsA[i]);
      gload_lds16(bsrc[i] + kt * 64, ldsB[i]);
    }
    __syncthreads();
#pragma unroll
    for (int ks = 0; ks < 2; ++ks) {
      int kc = ks * 4 + kg;
      s16x8 a[4], b[4];
#pragma unroll
      for (int m = 0; m < 4; ++m) {
        int row = wm * 64 + m * 16 + ar;
        a[m] = *(const s16x8*)&As[row * 64 + ((kc ^ (row & 7)) * 8)];
      }
#pragma unroll
      for (int n = 0; n < 4; ++n) {
        int row = wn * 64 + n * 16 + ar;
        b[n] = *(const s16x8*)&Bs[row * 64 + ((kc ^ (row & 7)) * 8)];
      }
#pragma unroll
      for (int m = 0; m < 4; ++m)
#pragma unroll
        for (int n = 0; n < 4; ++n)
          acc[m][n] = __builtin_amdgcn_mfma_f32_16x16x32_bf16(a[m], b[n], acc[m][n], 0, 0, 0);
    }
    __syncthreads();
  }

  // bias + relu -> LDS repack tile -> coalesced 16B stores (compact rows)
#pragma unroll
  for (int n = 0; n < 4; ++n) {
    int col = wn * 64 + n * 16 + ar;             // within-tile col
    float bb = b1[e * HID + bn + col];
#pragma unroll
    for (int m = 0; m < 4; ++m) {
      int rloc = wm * 64 + m * 16 + kg * 4;
#pragma unroll
      for (int r = 0; r < 4; ++r)
        smem[(rloc + r) * PADC + col] = f2bf(fmaxf(acc[m][n][r] + bb, 0.f));
    }
  }
  __syncthreads();
  int hbase = pfx + row0;
#pragma unroll
  for (int q = 0; q < 8; ++q) {
    int ci = tid + q * 256;
    int row = ci >> 4, ch = ci & 15;
    if (row0 + row < c) {
      int4 v = *(const int4*)&smem[row * PADC + ch * 8];
      *(int4*)&h[(size_t)(hbase + row) * HID + bn + ch * 8] = v;
    }
  }
}

// ---------------- expert layer 2 GEMM + rank-split partial store (or atomic fallback) ----------------
// 1D grid with XCD-aware decode: all 6 bn panels of one row-tile land on one XCD
// (consecutive XCD-local ids) so the A-tile (h rows) is re-read from L2, not L3.
template <bool STORE_PART>
__global__ __launch_bounds__(256) void k_ffn2(const unsigned short* __restrict__ h,
                                              const unsigned short* __restrict__ w2t,
                                              const float* __restrict__ b2,
                                              const int* __restrict__ cnt,
                                              const int* __restrict__ lists,
                                              const float* __restrict__ wts,
                                              unsigned short* __restrict__ part0,
                                              unsigned short* __restrict__ part1,
                                              float* __restrict__ out) {
  int id = blockIdx.x;
  int xcd = id & 7, local = id >> 3;
  int bny = local % 6;
  int r2 = local / 6;
  int xh = r2 & 31, e = r2 >> 5;
  int row0 = ((xh << 3) | xcd) * 128;
  int bn = bny * 128;

  int c = cnt[e * 32];
  if (row0 >= c) return;
  int pfx = 0;
#pragma unroll
  for (int j = 0; j < 8; ++j) if (j < e) pfx += cnt[j * 32];

  __shared__ __align__(16) unsigned short smem[128 * PADC];  // staging (32KB) U repack tile (36KB)
  __shared__ int stok[128];
  __shared__ float swt[128];
  unsigned short* As = smem;
  unsigned short* Bs = smem + 128 * 64;

  int tid = threadIdx.x;
  int lane = tid & 63;
  int wid = tid >> 6;
  int wm = wid >> 1, wn = wid & 1;
  int ar = lane & 15, kg = lane >> 4;

  if (tid < 128) {
    int r = row0 + tid;
    stok[tid] = (r < c) ? lists[e * NTOK + r] : 0;
    swt[tid]  = (r < c) ? wts[e * NTOK + r] : 0.f;
  }
  __syncthreads();

  const unsigned short* asrc[4];
  const unsigned short* bsrc[4];
  unsigned short* ldsA[4];
  unsigned short* ldsB[4];
#pragma unroll
  for (int i = 0; i < 4; ++i) {
    int cb0 = i * 256 + wid * 64;
    int ci = cb0 + lane;
    int row = ci >> 3;
    int cb = (ci & 7) ^ (row & 7);
    asrc[i] = h + (size_t)(pfx + row0 + row) * HID + cb * 8;
    bsrc[i] = w2t + ((size_t)e * DIM + bn + row) * HID + cb * 8;
    ldsA[i] = &As[cb0 * 8];
    ldsB[i] = &Bs[cb0 * 8];
  }

  f32x4 acc[4][4] = {};

  for (int kt = 0; kt < HID / 64; ++kt) {
#pragma unroll
    for (int i = 0; i < 4; ++i) {
      gload_lds16(asrc[i] + kt * 64, ldsA[i]);
      gload_lds16(bsrc[i] + kt * 64, ldsB[i]);
    }
    __syncthreads();
#pragma unroll
    for (int ks = 0; ks < 2; ++ks) {
      int kc = ks * 4 + kg;
      s16x8 a[4], b[4];
#pragma unroll
      for (int m = 0; m < 4; ++m) {
        int row = wm * 64 + m * 16 + ar;
        a[m] = *(const s16x8*)&As[row * 64 + ((kc ^ (row & 7)) * 8)];
      }
#pragma unroll
      for (int n = 0; n < 4; ++n) {
        int row = wn * 64 + n * 16 + ar;
        b[n] = *(const s16x8*)&Bs[row * 64 + ((kc ^ (row & 7)) * 8)];
      }
#pragma unroll
      for (int m = 0; m < 4; ++m)
#pragma unroll
        for (int n = 0; n < 4; ++n)
          acc[m][n] = __builtin_amdgcn_mfma_f32_16x16x32_bf16(a[m], b[n], acc[m][n], 0, 0, 0);
    }
    __syncthreads();
  }

  if constexpr (STORE_PART) {
    // weighted bias epilogue -> LDS repack tile -> coalesced 16B stores per token row
#pragma unroll
    for (int n = 0; n < 4; ++n) {
      int col = wn * 64 + n * 16 + ar;           // within-tile col
      float bb = b2[e * DIM + bn + col];
#pragma unroll
      for (int m = 0; m < 4; ++m) {
        int rloc = wm * 64 + m * 16 + kg * 4;
#pragma unroll
        for (int r = 0; r < 4; ++r) {
          float w = swt[rloc + r];
          smem[(rloc + r) * PADC + col] = f2bf((acc[m][n][r] + bb) * fabsf(w));
        }
      }
    }
    __syncthreads();
#pragma unroll
    for (int q = 0; q < 8; ++q) {
      int ci = tid + q * 256;
      int row = ci >> 4, ch = ci & 15;
      float w = swt[row];
      if (w != 0.f) {
        unsigned short* dst = (w > 0.f) ? part0 : part1;
        int4 v = *(const int4*)&smem[row * PADC + ch * 8];
        *(int4*)&dst[(size_t)stok[row] * DIM + bn + ch * 8] = v;
      }
    }
  } else {
    // atomic fallback
#pragma unroll
    for (int n = 0; n < 4; ++n) {
      int col = bn + wn * 64 + n * 16 + ar;
      float bb = b2[e * DIM + col];
#pragma unroll
      for (int m = 0; m < 4; ++m) {
        int rloc = wm * 64 + m * 16 + kg * 4;
#pragma unroll
        for (int r = 0; r < 4; ++r) {
          float w = swt[rloc + r];
          if (w != 0.f) {
            float v = (acc[m][n][r] + bb) * fabsf(w);
            atomicAdd(&out[(size_t)stok[rloc + r] * DIM + col], v);
          }
        }
      }
    }
  }
}

// ---------------- combine: out = part0 + part1 (streaming) ----------------
__global__ __launch_bounds__(256) void k_combine(const unsigned short* __restrict__ p0,
                                                 const unsigned short* __restrict__ p1,
                                                 float* __restrict__ out) {
  size_t i = ((size_t)blockIdx.x * 256 + threadIdx.x) * 8;
  int4 a = *(const int4*)(p0 + i);
  int4 b = *(const int4*)(p1 + i);
  unsigned int ua[4] = {(unsigned)a.x, (unsigned)a.y, (unsigned)a.z, (unsigned)a.w};
  unsigned int ub[4] = {(unsigned)b.x, (unsigned)b.y, (unsigned)b.z, (unsigned)b.w};
  float o[8];
#pragma unroll
  for (int q = 0; q < 4; ++q) {
    o[q * 2 + 0] = bf2f(ua[q] & 0xffffu) + bf2f(ub[q] & 0xffffu);
    o[q * 2 + 1] = bf2f(ua[q] >> 16)     + bf2f(ub[q] >> 16);
  }
  *(float4*)(out + i)     = *(float4*)&o[0];
  *(float4*)(out + i + 4) = *(float4*)&o[4];
}

extern "C" void kernel_launch(void* const* d_in, const int* in_sizes, int n_in,
                              void* d_out, int out_size, void* d_ws, size_t ws_size,
                              hipStream_t stream) {
  const float* x   = (const float*)d_in[0];
  const float* W1  = (const float*)d_in[1];
  const float* b1  = (const float*)d_in[2];
  const float* W2  = (const float*)d_in[3];
  const float* b2  = (const float*)d_in[4];
  const float* Wg1 = (const float*)d_in[5];
  const float* bg1 = (const float*)d_in[6];
  const float* Wg2 = (const float*)d_in[7];
  const float* bg2 = (const float*)d_in[8];
  float* out = (float*)d_out;                       // [N][768] then [N][8]
  float* gprob = out + (size_t)NTOK * DIM;

  char* ws = (char*)d_ws;
  size_t off = 0;
  auto alloc = [&](size_t bytes) { void* pp = ws + off; off += (bytes + 255) & ~(size_t)255; return pp; };
  unsigned short* xbf = (unsigned short*)alloc((size_t)NTOK * DIM * 2);
  unsigned short* w1t = (unsigned short*)alloc((size_t)NEXP * HID * DIM * 2);
  unsigned short* w2t = (unsigned short*)alloc((size_t)NEXP * DIM * HID * 2);
  float* hg = (float*)alloc((size_t)NTOK * HID * 4);
  int* cnt = (int*)alloc(NEXP * 32 * 4);            // 128B-padded counters
  int* lists = (int*)alloc((size_t)NEXP * NTOK * 4);
  float* wts = (float*)alloc((size_t)NEXP * NTOK * 4);
  unsigned short* part0 = (unsigned short*)alloc((size_t)NTOK * DIM * 2);
  unsigned short* part1 = (unsigned short*)alloc((size_t)NTOK * DIM * 2);
  bool store_mode = (off <= ws_size);

  // Gate scratch. In store_mode it overlays part0/part1 interiors: those are
  // written only by k_ffn2/k_combine, which run strictly AFTER every reader
  // of these aliases (stream order serializes). Fallback: dedicated allocs.
  unsigned short *xf16, *wg1t;
  float* gs; int* rcnt; int* rlist;
  if (store_mode) {
    xf16 = part1;
    wg1t = part0;                                    // [0, 384KB)
    char* p0b = (char*)part0;
    gs    = (float*)(p0b + (1u << 20));              // [1MB, 2MB)
    rcnt  = (int*)(p0b + 9 * (1u << 18));            // 2.25MB
    rlist = (int*)(p0b + 10 * (1u << 18));           // [2.5MB, +128KB)
  } else {
    xf16  = (unsigned short*)alloc((size_t)NTOK * DIM * 2);
    wg1t  = (unsigned short*)alloc((size_t)DIM * HID * 2);
    gs    = (float*)alloc((size_t)NTOK * 8 * 4);
    rcnt  = (int*)alloc(256);
    rlist = (int*)alloc((size_t)NTOK * 4);
  }

  // h (65536 compact rows x 256 bf16 = 32MB) reuses hg's 32MB (gate2a finishes first).
  unsigned short* h = (unsigned short*)hg;

  hipMemsetAsync(cnt, 0, NEXP * 32 * sizeof(int), stream);
  hipMemsetAsync(rcnt, 0, sizeof(int), stream);
  if (!store_mode)
    hipMemsetAsync(d_out, 0, (size_t)NTOK * DIM * sizeof(float), stream);

  k_cvt_x<<<(NTOK * DIM) / (256 * 8), 256, 0, stream>>>(x, xbf, xf16);
  k_trh<<<dim3(HID / 32, DIM / 32), 256, 0, stream>>>(Wg1, wg1t, DIM, HID);     // -> wg1t[h][d] fp16
  k_tr<<<dim3(HID / 32, DIM / 32, NEXP), 256, 0, stream>>>(W1, w1t, DIM, HID);  // -> w1t[e][h][d]
  k_tr<<<dim3(DIM / 32, HID / 32, NEXP), 256, 0, stream>>>(W2, w2t, HID, DIM);  // -> w2t[e][d][h]
  k_gmfma<<<dim3(NTOK / 128, HID / 128), 256, 0, stream>>>(xf16, wg1t, bg1, hg);
  k_gate2a<<<NTOK / 256, 256, 0, stream>>>(hg, Wg2, bg2, gs, rcnt, rlist);
  k_rescue<<<2048, 256, 0, stream>>>(x, Wg1, bg1, Wg2, bg2, rcnt, rlist, gs);
  k_gate2b<<<NTOK / 256, 256, 0, stream>>>(gs, gprob, cnt, lists, wts);
  k_ffn1<<<(NTOK / 128) * 2 * NEXP, 256, 0, stream>>>(xbf, w1t, b1, cnt, lists, h);
  if (store_mode) {
    k_ffn2<true><<<(NTOK / 128) * 6 * NEXP, 256, 0, stream>>>(h, w2t, b2, cnt, lists, wts, part0, part1, out);
    k_combine<<<(NTOK * DIM) / (256 * 8), 256, 0, stream>>>(part0, part1, out);
  } else {
    k_ffn2<false><<<(NTOK / 128) * 6 * NEXP, 256, 0, stream>>>(h, w2t, b2, cnt, lists, wts, part0, part1, out);
  }
}

// Round 16
// 247.317 us; speedup vs baseline: 1.6353x; 1.0500x over previous
//
#include <hip/hip_runtime.h>
#include <hip/hip_bf16.h>
#include <stdint.h>

#define NTOK 32768
#define DIM  768
#define HID  256
#define NEXP 8
#define PADC 144   // repack-tile column pad: conflict-reduced epilogue writes

typedef float f32x4 __attribute__((ext_vector_type(4)));
typedef short s16x8 __attribute__((ext_vector_type(8)));

__device__ __forceinline__ unsigned short f2bf(float f) {
  union { float f; unsigned int u; } c; c.f = f;
  unsigned int r = c.u + 0x7fffu + ((c.u >> 16) & 1u);
  return (unsigned short)(r >> 16);
}

__device__ __forceinline__ float bf2f(unsigned int u) {
  union { unsigned int x; float f; } c; c.x = u << 16; return c.f;
}

__device__ __forceinline__ unsigned short f2h(float f) {
  union { _Float16 h; unsigned short u; } c; c.h = (_Float16)f; return c.u;
}

__device__ __forceinline__ float h2f(unsigned short u) {
  union { unsigned short u; _Float16 h; } c; c.u = u; return (float)c.h;
}

// async global -> LDS, 16B per lane. LDS dest is wave-uniform base + lane*16.
__device__ __forceinline__ void gload_lds16(const unsigned short* g, unsigned short* l) {
  __builtin_amdgcn_global_load_lds((const __attribute__((address_space(1))) void*)g,
                                   (__attribute__((address_space(3))) void*)l, 16, 0, 0);
}

// ---------------- x fp32 -> fp16 (gate + experts) ----------------
__global__ __launch_bounds__(256) void k_cvt_x(const float* __restrict__ x,
                                               unsigned short* __restrict__ xf16) {
  int i = (blockIdx.x * 256 + threadIdx.x) * 8;
  float4 a = *(const float4*)(x + i);
  float4 b = *(const float4*)(x + i + 4);
  float f[8] = {a.x, a.y, a.z, a.w, b.x, b.y, b.z, b.w};
  unsigned short hh[8];
#pragma unroll
  for (int q = 0; q < 8; ++q) hh[q] = f2h(f[q]);
  int4 vh;
  vh.x = (int)((unsigned)hh[0] | ((unsigned)hh[1] << 16));
  vh.y = (int)((unsigned)hh[2] | ((unsigned)hh[3] << 16));
  vh.z = (int)((unsigned)hh[4] | ((unsigned)hh[5] << 16));
  vh.w = (int)((unsigned)hh[6] | ((unsigned)hh[7] << 16));
  *(int4*)(xf16 + i) = vh;
}

// ---------------- fp32 [R][C] -> fp16 [C][R] transpose via LDS tile (per-e slab) ----------------
__global__ __launch_bounds__(256) void k_trh(const float* __restrict__ in,
                                             unsigned short* __restrict__ outp,
                                             int R, int C) {
  __shared__ float tile[32][33];
  int e = blockIdx.z;
  const float* ip = in + (size_t)e * R * C;
  unsigned short* op = outp + (size_t)e * R * C;
  int tx = threadIdx.x & 31, ty = threadIdx.x >> 5;  // 32x8
  int r0 = blockIdx.y * 32, c0 = blockIdx.x * 32;
#pragma unroll
  for (int i = 0; i < 4; ++i)
    tile[ty + i * 8][tx] = ip[(size_t)(r0 + ty + i * 8) * C + c0 + tx];
  __syncthreads();
#pragma unroll
  for (int i = 0; i < 4; ++i)
    op[(size_t)(c0 + ty + i * 8) * R + r0 + tx] = f2h(tile[tx][ty + i * 8]);
}

// ---------------- gate layer 1, fp16 MFMA: hg(fp16) = relu(x @ Wg1 + bg1) ----------------
// fp16 MFMA error sigma ~6e-5 + fp16-h storage sigma ~5e-5: 1e-3 rescue threshold >= 10 sigma.
__global__ __launch_bounds__(256) void k_gmfma(const unsigned short* __restrict__ xh,
                                               const unsigned short* __restrict__ wh,
                                               const float* __restrict__ bg1,
                                               unsigned short* __restrict__ hg) {
  int bm = blockIdx.x * 128;
  int bn = blockIdx.y * 128;

  __shared__ __align__(16) unsigned short Ah[128 * 64];
  __shared__ __align__(16) unsigned short Bh[128 * 64];

  int tid = threadIdx.x;
  int lane = tid & 63;
  int wid = tid >> 6;
  int wm = wid >> 1, wn = wid & 1;
  int ar = lane & 15, kg = lane >> 4;

  const unsigned short *sah[4], *sbh[4];
  unsigned short *dA[4], *dB[4];
#pragma unroll
  for (int i = 0; i < 4; ++i) {
    int cb0 = i * 256 + wid * 64;        // wave-uniform chunk base
    int ci = cb0 + lane;
    int row = ci >> 3;
    int cb = (ci & 7) ^ (row & 7);       // inverse-swizzled source chunk
    sah[i] = xh + (size_t)(bm + row) * DIM + cb * 8;
    sbh[i] = wh + (size_t)(bn + row) * DIM + cb * 8;
    dA[i] = &Ah[cb0 * 8];
    dB[i] = &Bh[cb0 * 8];
  }

  f32x4 acc[4][4] = {};

  for (int kt = 0; kt < DIM / 64; ++kt) {
#pragma unroll
    for (int i = 0; i < 4; ++i) {
      gload_lds16(sah[i] + kt * 64, dA[i]);
      gload_lds16(sbh[i] + kt * 64, dB[i]);
    }
    __syncthreads();
#pragma unroll
    for (int ks = 0; ks < 2; ++ks) {
      int kc = ks * 4 + kg;
      s16x8 a[4], b[4];
#pragma unroll
      for (int m = 0; m < 4; ++m) {
        int row = wm * 64 + m * 16 + ar;
        a[m] = *(const s16x8*)&Ah[row * 64 + ((kc ^ (row & 7)) * 8)];
      }
#pragma unroll
      for (int n = 0; n < 4; ++n) {
        int row = wn * 64 + n * 16 + ar;
        b[n] = *(const s16x8*)&Bh[row * 64 + ((kc ^ (row & 7)) * 8)];
      }
#pragma unroll
      for (int m = 0; m < 4; ++m)
#pragma unroll
        for (int n = 0; n < 4; ++n)
          acc[m][n] = __builtin_amdgcn_mfma_f32_16x16x32_f16(a[m], b[n], acc[m][n], 0, 0, 0);
    }
    __syncthreads();
  }

  // bias + relu -> hg fp16
#pragma unroll
  for (int n = 0; n < 4; ++n) {
    int col = bn + wn * 64 + n * 16 + ar;
    float bb = bg1[col];
#pragma unroll
    for (int m = 0; m < 4; ++m) {
      int rbase = bm + wm * 64 + m * 16 + kg * 4;
#pragma unroll
      for (int r = 0; r < 4; ++r)
        hg[(size_t)(rbase + r) * HID + col] = f2h(fmaxf(acc[m][n][r] + bb, 0.f));
    }
  }
}

// ---------------- gate 2a: scores from hg(fp16) -> gs; flag near-ties for fp32 rescue ----------------
__global__ __launch_bounds__(256) void k_gate2a(const unsigned short* __restrict__ hg,
                                                const float* __restrict__ wg2,
                                                const float* __restrict__ bg2,
                                                float* __restrict__ gs,
                                                int* __restrict__ rcnt,
                                                int* __restrict__ rlist) {
  int tok = blockIdx.x * 256 + threadIdx.x;
  const unsigned short* hrow = hg + (size_t)tok * HID;

  float s[8];
#pragma unroll
  for (int e = 0; e < 8; ++e) s[e] = bg2[e];
#pragma unroll 4
  for (int j = 0; j < 32; ++j) {
    s16x8 hv8 = *(const s16x8*)(hrow + j * 8);
#pragma unroll
    for (int i = 0; i < 8; ++i) {
      float hv = h2f((unsigned short)hv8[i]);
      const float* wr = wg2 + (j * 8 + i) * 8;
#pragma unroll
      for (int e = 0; e < 8; ++e) s[e] += hv * wr[e];
    }
  }

  f32x4 o0 = {s[0], s[1], s[2], s[3]};
  f32x4 o1 = {s[4], s[5], s[6], s[7]};
  *(f32x4*)&gs[(size_t)tok * 8] = o0;
  *(f32x4*)&gs[(size_t)tok * 8 + 4] = o1;

  // top-3 scan; fp16-gate score-gap error sigma ~1e-4. 1e-3 threshold = 10 sigma:
  // tokens outside the window cannot flip their top-2 set; inside -> exact fp32.
  float m1 = -3e38f, m2 = -3e38f, m3 = -3e38f;
#pragma unroll
  for (int e = 0; e < 8; ++e) {
    float v = s[e];
    if (v > m1)      { m3 = m2; m2 = m1; m1 = v; }
    else if (v > m2) { m3 = m2; m2 = v; }
    else if (v > m3) { m3 = v; }
  }
  if (m2 - m3 < 1e-3f) {
    int i = atomicAdd(rcnt, 1);
    rlist[i] = tok;
  }
}

// ---------------- rescue: exact fp32 gate recompute for flagged tokens ----------------
__global__ __launch_bounds__(256) void k_rescue(const float* __restrict__ x,
                                                const float* __restrict__ wg1,
                                                const float* __restrict__ bg1,
                                                const float* __restrict__ wg2,
                                                const float* __restrict__ bg2,
                                                const int* __restrict__ rcnt,
                                                const int* __restrict__ rlist,
                                                float* __restrict__ gs) {
  __shared__ float xs[DIM];
  __shared__ float ps[4][8];
  int n = rcnt[0];
  int tid = threadIdx.x;
  int lane = tid & 63, wid = tid >> 6;
  for (int idx = blockIdx.x; idx < n; idx += 2048) {
    int tok = rlist[idx];
    __syncthreads();  // protect xs/ps reuse across iterations
#pragma unroll
    for (int q = 0; q < 3; ++q) xs[tid + q * 256] = x[(size_t)tok * DIM + tid + q * 256];
    __syncthreads();
    const float* wcol = wg1 + tid;               // tid = hidden unit (HID==256)
    float pa[8] = {};
#pragma unroll 4
    for (int k0 = 0; k0 < DIM; k0 += 8) {
#pragma unroll
      for (int q = 0; q < 8; ++q)
        pa[q] = fmaf(xs[k0 + q], wcol[(size_t)(k0 + q) * HID], pa[q]);
    }
    float acc = bg1[tid] +
                (((pa[0] + pa[1]) + (pa[2] + pa[3])) + ((pa[4] + pa[5]) + (pa[6] + pa[7])));
    float hj = fmaxf(acc, 0.f);
    float p[8];
#pragma unroll
    for (int e = 0; e < 8; ++e) p[e] = hj * wg2[tid * 8 + e];
#pragma unroll
    for (int off = 32; off >= 1; off >>= 1) {
#pragma unroll
      for (int e = 0; e < 8; ++e) p[e] += __shfl_xor(p[e], off);
    }
    if (lane == 0) {
#pragma unroll
      for (int e = 0; e < 8; ++e) ps[wid][e] = p[e];
    }
    __syncthreads();
    if (tid < 8)
      gs[(size_t)tok * 8 + tid] = bg2[tid] + ps[0][tid] + ps[1][tid] + ps[2][tid] + ps[3][tid];
  }
}

// ---------------- gate 2b: softmax + top2 + routing lists from gs ----------------
// wts sign-encodes rank: +w for top-1 expert entry, -w for top-2 entry.
__global__ __launch_bounds__(256) void k_gate2b(const float* __restrict__ gs,
                                                float* __restrict__ gprob,
                                                int* __restrict__ cnt,     // stride 32
                                                int* __restrict__ lists,
                                                float* __restrict__ wts) {
  __shared__ int lcnt[8];
  __shared__ int sbase[8];
  __shared__ int se1[256], se2[256], sp1[256], sp2[256];
  __shared__ float sw1[256], sw2[256];
  int tid = threadIdx.x;
  if (tid < 8) lcnt[tid] = 0;
  __syncthreads();

  int tok = blockIdx.x * 256 + tid;
  f32x4 s0v = *(const f32x4*)&gs[(size_t)tok * 8];
  f32x4 s1v = *(const f32x4*)&gs[(size_t)tok * 8 + 4];
  float s[8] = {s0v[0], s0v[1], s0v[2], s0v[3], s1v[0], s1v[1], s1v[2], s1v[3]};

  float m = s[0];
#pragma unroll
  for (int e = 1; e < 8; ++e) m = fmaxf(m, s[e]);
  float p[8]; float sum = 0.f;
#pragma unroll
  for (int e = 0; e < 8; ++e) { p[e] = expf(s[e] - m); sum += p[e]; }
  float inv = 1.f / sum;
#pragma unroll
  for (int e = 0; e < 8; ++e) p[e] *= inv;

  f32x4 o0 = {p[0], p[1], p[2], p[3]};
  f32x4 o1 = {p[4], p[5], p[6], p[7]};
  *(f32x4*)&gprob[(size_t)tok * 8] = o0;
  *(f32x4*)&gprob[(size_t)tok * 8 + 4] = o1;

  int e1 = 0; float p1 = p[0];
#pragma unroll
  for (int e = 1; e < 8; ++e) if (p[e] > p1) { p1 = p[e]; e1 = e; }
  int e2 = -1; float p2 = -1.f;
#pragma unroll
  for (int e = 0; e < 8; ++e) if (e != e1 && p[e] > p2) { p2 = p[e]; e2 = e; }
  float rinv = 1.f / (p1 + p2);

  int pos1 = atomicAdd(&lcnt[e1], 1);
  int pos2 = atomicAdd(&lcnt[e2], 1);
  se1[tid] = e1; sp1[tid] = pos1; sw1[tid] = p1 * rinv;
  se2[tid] = e2; sp2[tid] = pos2; sw2[tid] = p2 * rinv;
  __syncthreads();

  if (tid < 8) sbase[tid] = atomicAdd(&cnt[tid * 32], lcnt[tid]);
  __syncthreads();

  int a1i = sbase[se1[tid]] + sp1[tid];
  lists[se1[tid] * NTOK + a1i] = tok; wts[se1[tid] * NTOK + a1i] = sw1[tid];   // rank0: +w
  int a2i = sbase[se2[tid]] + sp2[tid];
  lists[se2[tid] * NTOK + a2i] = tok; wts[se2[tid] * NTOK + a2i] = -sw2[tid];  // rank1: -w
}

// ---------------- expert layer 1 GEMM (fp16): h = relu(x_gathered @ W1^T + b1) ----------------
// 1D grid with XCD-aware decode: both bn panels of one row-tile land on one XCD.
__global__ __launch_bounds__(256) void k_ffn1(const unsigned short* __restrict__ xf16,
                                              const unsigned short* __restrict__ w1t,
                                              const float* __restrict__ b1,
                                              const int* __restrict__ cnt,
                                              const int* __restrict__ lists,
                                              unsigned short* __restrict__ h) {
  int id = blockIdx.x;
  int xcd = id & 7, local = id >> 3;
  int bny = local & 1;
  int r2 = local >> 1;
  int xh = r2 & 31, e = r2 >> 5;
  int row0 = ((xh << 3) | xcd) * 128;
  int bn = bny * 128;

  int c = cnt[e * 32];
  if (row0 >= c) return;
  int pfx = 0;
#pragma unroll
  for (int j = 0; j < 8; ++j) if (j < e) pfx += cnt[j * 32];

  __shared__ __align__(16) unsigned short smem[128 * PADC];  // staging (32KB) U repack tile (36KB)
  __shared__ int stok[128];
  unsigned short* As = smem;
  unsigned short* Bs = smem + 128 * 64;

  int tid = threadIdx.x;
  int lane = tid & 63;
  int wid = tid >> 6;
  int wm = wid >> 1, wn = wid & 1;
  int ar = lane & 15, kg = lane >> 4;

  if (tid < 128) stok[tid] = lists[e * NTOK + min(row0 + tid, c - 1)];
  __syncthreads();

  const unsigned short* asrc[4];
  const unsigned short* bsrc[4];
  unsigned short* ldsA[4];
  unsigned short* ldsB[4];
#pragma unroll
  for (int i = 0; i < 4; ++i) {
    int cb0 = i * 256 + wid * 64;        // wave-uniform chunk base
    int ci = cb0 + lane;
    int row = ci >> 3;
    int cb = (ci & 7) ^ (row & 7);       // inverse-swizzled source chunk
    asrc[i] = xf16 + (size_t)stok[row] * DIM + cb * 8;
    bsrc[i] = w1t + ((size_t)e * HID + bn + row) * DIM + cb * 8;
    ldsA[i] = &As[cb0 * 8];
    ldsB[i] = &Bs[cb0 * 8];
  }

  f32x4 acc[4][4] = {};

  for (int kt = 0; kt < DIM / 64; ++kt) {
#pragma unroll
    for (int i = 0; i < 4; ++i) {
      gload_lds16(asrc[i] + kt * 64, ldsA[i]);
      gload_lds16(bsrc[i] + kt * 64, ldsB[i]);
    }
    __syncthreads();
#pragma unroll
    for (int ks = 0; ks < 2; ++ks) {
      int kc = ks * 4 + kg;
      s16x8 a[4], b[4];
#pragma unroll
      for (int m = 0; m < 4; ++m) {
        int row = wm * 64 + m * 16 + ar;
        a[m] = *(const s16x8*)&As[row * 64 + ((kc ^ (row & 7)) * 8)];
      }
#pragma unroll
      for (int n = 0; n < 4; ++n) {
        int row = wn * 64 + n * 16 + ar;
        b[n] = *(const s16x8*)&Bs[row * 64 + ((kc ^ (row & 7)) * 8)];
      }
#pragma unroll
      for (int m = 0; m < 4; ++m)
#pragma unroll
        for (int n = 0; n < 4; ++n)
          acc[m][n] = __builtin_amdgcn_mfma_f32_16x16x32_f16(a[m], b[n], acc[m][n], 0, 0, 0);
    }
    __syncthreads();
  }

  // bias + relu -> LDS repack tile -> coalesced 16B stores (compact rows, fp16)
#pragma unroll
  for (int n = 0; n < 4; ++n) {
    int col = wn * 64 + n * 16 + ar;             // within-tile col
    float bb = b1[e * HID + bn + col];
#pragma unroll
    for (int m = 0; m < 4; ++m) {
      int rloc = wm * 64 + m * 16 + kg * 4;
#pragma unroll
      for (int r = 0; r < 4; ++r)
        smem[(rloc + r) * PADC + col] = f2h(fmaxf(acc[m][n][r] + bb, 0.f));
    }
  }
  __syncthreads();
  int hbase = pfx + row0;
#pragma unroll
  for (int q = 0; q < 8; ++q) {
    int ci = tid + q * 256;
    int row = ci >> 4, ch = ci & 15;
    if (row0 + row < c) {
      int4 v = *(const int4*)&smem[row * PADC + ch * 8];
      *(int4*)&h[(size_t)(hbase + row) * HID + bn + ch * 8] = v;
    }
  }
}

// ---------------- expert layer 2 GEMM (fp16) + rank-split partial store ----------------
// 1D grid with XCD-aware decode: all 6 bn panels of one row-tile land on one XCD.
template <bool STORE_PART>
__global__ __launch_bounds__(256) void k_ffn2(const unsigned short* __restrict__ h,
                                              const unsigned short* __restrict__ w2t,
                                              const float* __restrict__ b2,
                                              const int* __restrict__ cnt,
                                              const int* __restrict__ lists,
                                              const float* __restrict__ wts,
                                              unsigned short* __restrict__ part0,
                                              unsigned short* __restrict__ part1,
                                              float* __restrict__ out) {
  int id = blockIdx.x;
  int xcd = id & 7, local = id >> 3;
  int bny = local % 6;
  int r2 = local / 6;
  int xh = r2 & 31, e = r2 >> 5;
  int row0 = ((xh << 3) | xcd) * 128;
  int bn = bny * 128;

  int c = cnt[e * 32];
  if (row0 >= c) return;
  int pfx = 0;
#pragma unroll
  for (int j = 0; j < 8; ++j) if (j < e) pfx += cnt[j * 32];

  __shared__ __align__(16) unsigned short smem[128 * PADC];  // staging (32KB) U repack tile (36KB)
  __shared__ int stok[128];
  __shared__ float swt[128];
  unsigned short* As = smem;
  unsigned short* Bs = smem + 128 * 64;

  int tid = threadIdx.x;
  int lane = tid & 63;
  int wid = tid >> 6;
  int wm = wid >> 1, wn = wid & 1;
  int ar = lane & 15, kg = lane >> 4;

  if (tid < 128) {
    int r = row0 + tid;
    stok[tid] = (r < c) ? lists[e * NTOK + r] : 0;
    swt[tid]  = (r < c) ? wts[e * NTOK + r] : 0.f;
  }
  __syncthreads();

  const unsigned short* asrc[4];
  const unsigned short* bsrc[4];
  unsigned short* ldsA[4];
  unsigned short* ldsB[4];
#pragma unroll
  for (int i = 0; i < 4; ++i) {
    int cb0 = i * 256 + wid * 64;
    int ci = cb0 + lane;
    int row = ci >> 3;
    int cb = (ci & 7) ^ (row & 7);
    asrc[i] = h + (size_t)(pfx + row0 + row) * HID + cb * 8;
    bsrc[i] = w2t + ((size_t)e * DIM + bn + row) * HID + cb * 8;
    ldsA[i] = &As[cb0 * 8];
    ldsB[i] = &Bs[cb0 * 8];
  }

  f32x4 acc[4][4] = {};

  for (int kt = 0; kt < HID / 64; ++kt) {
#pragma unroll
    for (int i = 0; i < 4; ++i) {
      gload_lds16(asrc[i] + kt * 64, ldsA[i]);
      gload_lds16(bsrc[i] + kt * 64, ldsB[i]);
    }
    __syncthreads();
#pragma unroll
    for (int ks = 0; ks < 2; ++ks) {
      int kc = ks * 4 + kg;
      s16x8 a[4], b[4];
#pragma unroll
      for (int m = 0; m < 4; ++m) {
        int row = wm * 64 + m * 16 + ar;
        a[m] = *(const s16x8*)&As[row * 64 + ((kc ^ (row & 7)) * 8)];
      }
#pragma unroll
      for (int n = 0; n < 4; ++n) {
        int row = wn * 64 + n * 16 + ar;
        b[n] = *(const s16x8*)&Bs[row * 64 + ((kc ^ (row & 7)) * 8)];
      }
#pragma unroll
      for (int m = 0; m < 4; ++m)
#pragma unroll
        for (int n = 0; n < 4; ++n)
          acc[m][n] = __builtin_amdgcn_mfma_f32_16x16x32_f16(a[m], b[n], acc[m][n], 0, 0, 0);
    }
    __syncthreads();
  }

  if constexpr (STORE_PART) {
    // weighted bias epilogue -> LDS repack tile -> coalesced 16B stores per token row
#pragma unroll
    for (int n = 0; n < 4; ++n) {
      int col = wn * 64 + n * 16 + ar;           // within-tile col
      float bb = b2[e * DIM + bn + col];
#pragma unroll
      for (int m = 0; m < 4; ++m) {
        int rloc = wm * 64 + m * 16 + kg * 4;
#pragma unroll
        for (int r = 0; r < 4; ++r) {
          float w = swt[rloc + r];
          smem[(rloc + r) * PADC + col] = f2bf((acc[m][n][r] + bb) * fabsf(w));
        }
      }
    }
    __syncthreads();
#pragma unroll
    for (int q = 0; q < 8; ++q) {
      int ci = tid + q * 256;
      int row = ci >> 4, ch = ci & 15;
      float w = swt[row];
      if (w != 0.f) {
        unsigned short* dst = (w > 0.f) ? part0 : part1;
        int4 v = *(const int4*)&smem[row * PADC + ch * 8];
        *(int4*)&dst[(size_t)stok[row] * DIM + bn + ch * 8] = v;
      }
    }
  } else {
    // atomic fallback
#pragma unroll
    for (int n = 0; n < 4; ++n) {
      int col = bn + wn * 64 + n * 16 + ar;
      float bb = b2[e * DIM + col];
#pragma unroll
      for (int m = 0; m < 4; ++m) {
        int rloc = wm * 64 + m * 16 + kg * 4;
#pragma unroll
        for (int r = 0; r < 4; ++r) {
          float w = swt[rloc + r];
          if (w != 0.f) {
            float v = (acc[m][n][r] + bb) * fabsf(w);
            atomicAdd(&out[(size_t)stok[rloc + r] * DIM + col], v);
          }
        }
      }
    }
  }
}

// ---------------- combine: out = part0 + part1 (streaming) ----------------
__global__ __launch_bounds__(256) void k_combine(const unsigned short* __restrict__ p0,
                                                 const unsigned short* __restrict__ p1,
                                                 float* __restrict__ out) {
  size_t i = ((size_t)blockIdx.x * 256 + threadIdx.x) * 8;
  int4 a = *(const int4*)(p0 + i);
  int4 b = *(const int4*)(p1 + i);
  unsigned int ua[4] = {(unsigned)a.x, (unsigned)a.y, (unsigned)a.z, (unsigned)a.w};
  unsigned int ub[4] = {(unsigned)b.x, (unsigned)b.y, (unsigned)b.z, (unsigned)b.w};
  float o[8];
#pragma unroll
  for (int q = 0; q < 4; ++q) {
    o[q * 2 + 0] = bf2f(ua[q] & 0xffffu) + bf2f(ub[q] & 0xffffu);
    o[q * 2 + 1] = bf2f(ua[q] >> 16)     + bf2f(ub[q] >> 16);
  }
  *(float4*)(out + i)     = *(float4*)&o[0];
  *(float4*)(out + i + 4) = *(float4*)&o[4];
}

extern "C" void kernel_launch(void* const* d_in, const int* in_sizes, int n_in,
                              void* d_out, int out_size, void* d_ws, size_t ws_size,
                              hipStream_t stream) {
  const float* x   = (const float*)d_in[0];
  const float* W1  = (const float*)d_in[1];
  const float* b1  = (const float*)d_in[2];
  const float* W2  = (const float*)d_in[3];
  const float* b2  = (const float*)d_in[4];
  const float* Wg1 = (const float*)d_in[5];
  const float* bg1 = (const float*)d_in[6];
  const float* Wg2 = (const float*)d_in[7];
  const float* bg2 = (const float*)d_in[8];
  float* out = (float*)d_out;                       // [N][768] then [N][8]
  float* gprob = out + (size_t)NTOK * DIM;

  char* ws = (char*)d_ws;
  size_t off = 0;
  auto alloc = [&](size_t bytes) { void* pp = ws + off; off += (bytes + 255) & ~(size_t)255; return pp; };
  unsigned short* w1t = (unsigned short*)alloc((size_t)NEXP * HID * DIM * 2);
  unsigned short* w2t = (unsigned short*)alloc((size_t)NEXP * DIM * HID * 2);
  float* hgbuf = (float*)alloc((size_t)NTOK * HID * 4);   // hg (fp16, 16MB) U h (fp16, 32MB)
  int* cnt = (int*)alloc(NEXP * 32 * 4);            // 128B-padded counters
  int* lists = (int*)alloc((size_t)NEXP * NTOK * 4);
  float* wts = (float*)alloc((size_t)NEXP * NTOK * 4);
  unsigned short* part0 = (unsigned short*)alloc((size_t)NTOK * DIM * 2);
  unsigned short* part1 = (unsigned short*)alloc((size_t)NTOK * DIM * 2);
  bool store_mode = (off <= ws_size);

  // Gate scratch. In store_mode it overlays part0/part1 interiors: those are
  // written only by k_ffn2/k_combine, which run strictly AFTER every reader
  // of these aliases (stream order serializes: cvt_x..ffn1 all precede ffn2).
  unsigned short *xf16, *wg1t;
  float* gs; int* rcnt; int* rlist;
  if (store_mode) {
    xf16 = part1;                                    // 50MB region, last read by k_ffn1
    wg1t = part0;                                    // [0, 384KB)
    char* p0b = (char*)part0;
    gs    = (float*)(p0b + (1u << 20));              // [1MB, 2MB)
    rcnt  = (int*)(p0b + 9 * (1u << 18));            // 2.25MB
    rlist = (int*)(p0b + 10 * (1u << 18));           // [2.5MB, +128KB)
  } else {
    xf16  = (unsigned short*)alloc((size_t)NTOK * DIM * 2);
    wg1t  = (unsigned short*)alloc((size_t)DIM * HID * 2);
    gs    = (float*)alloc((size_t)NTOK * 8 * 4);
    rcnt  = (int*)alloc(256);
    rlist = (int*)alloc((size_t)NTOK * 4);
  }

  unsigned short* hg = (unsigned short*)hgbuf;       // fp16 gate hidden (16MB)
  unsigned short* h = (unsigned short*)hgbuf;        // fp16 compact expert hidden (32MB), after gate done

  hipMemsetAsync(cnt, 0, NEXP * 32 * sizeof(int), stream);
  hipMemsetAsync(rcnt, 0, sizeof(int), stream);
  if (!store_mode)
    hipMemsetAsync(d_out, 0, (size_t)NTOK * DIM * sizeof(float), stream);

  k_cvt_x<<<(NTOK * DIM) / (256 * 8), 256, 0, stream>>>(x, xf16);
  k_trh<<<dim3(HID / 32, DIM / 32, 1), 256, 0, stream>>>(Wg1, wg1t, DIM, HID);   // -> wg1t[h][d]
  k_trh<<<dim3(HID / 32, DIM / 32, NEXP), 256, 0, stream>>>(W1, w1t, DIM, HID);  // -> w1t[e][h][d]
  k_trh<<<dim3(DIM / 32, HID / 32, NEXP), 256, 0, stream>>>(W2, w2t, HID, DIM);  // -> w2t[e][d][h]
  k_gmfma<<<dim3(NTOK / 128, HID / 128), 256, 0, stream>>>(xf16, wg1t, bg1, hg);
  k_gate2a<<<NTOK / 256, 256, 0, stream>>>(hg, Wg2, bg2, gs, rcnt, rlist);
  k_rescue<<<2048, 256, 0, stream>>>(x, Wg1, bg1, Wg2, bg2, rcnt, rlist, gs);
  k_gate2b<<<NTOK / 256, 256, 0, stream>>>(gs, gprob, cnt, lists, wts);
  k_ffn1<<<(NTOK / 128) * 2 * NEXP, 256, 0, stream>>>(xf16, w1t, b1, cnt, lists, h);
  if (store_mode) {
    k_ffn2<true><<<(NTOK / 128) * 6 * NEXP, 256, 0, stream>>>(h, w2t, b2, cnt, lists, wts, part0, part1, out);
    k_combine<<<(NTOK * DIM) / (256 * 8), 256, 0, stream>>>(part0, part1, out);
  } else {
    k_ffn2<false><<<(NTOK / 128) * 6 * NEXP, 256, 0, stream>>>(h, w2t, b2, cnt, lists, wts, part0, part1, out);
  }
}